// Round 7
// baseline (1262.594 us; speedup 1.0000x reference)
//
#include <hip/hip_runtime.h>
#include <math.h>

#define N_NODES  25000
#define N_EDGES  300000
#define N_GRAPHS 256
#define EMB_DIM  92
#define HID      256

typedef short bf16x8 __attribute__((ext_vector_type(8)));
typedef float f32x4  __attribute__((ext_vector_type(4)));

// fast softplus == jax.nn.softplus to ~1e-6 abs
__device__ __forceinline__ float softplusf(float x){
    return fmaxf(x, 0.0f) + __logf(1.0f + __expf(-fabsf(x)));
}
__device__ __forceinline__ unsigned short f2bf(float f){
    unsigned int u = __float_as_uint(f);
    unsigned int r = (u + 0x7FFFu + ((u >> 16) & 1u)) >> 16;   // RNE
    return (unsigned short)r;
}
__device__ __forceinline__ float bf2f(unsigned short b){
    return __uint_as_float(((unsigned int)b) << 16);
}
// truncation hi/lo split (used for node-update A operand; 3-MFMA scheme)
__device__ __forceinline__ void split_bf(float h, unsigned short& hi, unsigned short& lo){
    const unsigned int u = __float_as_uint(h);
    hi = (unsigned short)(u >> 16);
    const float r = h - __uint_as_float(u & 0xFFFF0000u);
    lo = (unsigned short)(__float_as_uint(r) >> 16);
}
// XCD-contiguity swizzle: under round-robin blockIdx->XCD dispatch, gives each
// XCD a contiguous range of windows (dst-sorted edge ranges) so agg atomics
// stay in one L2. Perf heuristic only — any mapping is correct.
__device__ __forceinline__ int xcd_window(int nwin){
    const int per = (nwin + 7) >> 3;
    const int win = (blockIdx.x & 7) * per + (blockIdx.x >> 3);
    return (win < nwin) ? win : -1;
}

// ---------------------------------------------------------------- embedding gather
__global__ void gather_emb_kernel(const int* __restrict__ atoms,
                                  const float* __restrict__ emb,
                                  float* __restrict__ x)
{
    const int n = blockIdx.x;
    const int c = threadIdx.x;
    if (c < EMB_DIM){
        const int a = atoms[n];
        x[(size_t)n*EMB_DIM + c] = emb[(size_t)a*EMB_DIM + c];
    }
}

// ---------------------------------------------------------------- counting sort by dst
__global__ __launch_bounds__(256) void hist_kernel(const int* __restrict__ dst, int* __restrict__ hist){
    const int e = blockIdx.x*256 + threadIdx.x;
    if (e < N_EDGES) atomicAdd(&hist[dst[e]], 1);
}

__global__ __launch_bounds__(1024) void scan_kernel(const int* __restrict__ hist, int* __restrict__ cursor){
    __shared__ int chunk[1024];
    const int t = threadIdx.x;
    const int base = t*25;                     // 1024*25 = 25600 >= 25000
    int local[25];
    int s = 0;
    #pragma unroll
    for (int i=0;i<25;i++){
        const int idx = base+i;
        const int v = (idx < N_NODES) ? hist[idx] : 0;
        local[i] = s; s += v;
    }
    chunk[t] = s;
    __syncthreads();
    for (int off=1; off<1024; off<<=1){
        int v = (t >= off) ? chunk[t-off] : 0;
        __syncthreads();
        chunk[t] += v;
        __syncthreads();
    }
    const int pre = (t > 0) ? chunk[t-1] : 0;
    #pragma unroll
    for (int i=0;i<25;i++){
        const int idx = base+i;
        if (idx < N_NODES) cursor[idx] = pre + local[i];
    }
}

__global__ __launch_bounds__(256) void scatter_kernel(const int* __restrict__ src, const int* __restrict__ dst,
                                                      int* __restrict__ cursor,
                                                      int* __restrict__ perm_s, int* __restrict__ src_s,
                                                      int* __restrict__ dst_s){
    const int e = blockIdx.x*256 + threadIdx.x;
    if (e < N_EDGES){
        const int d = dst[e];
        const int pos = atomicAdd(&cursor[d], 1);
        perm_s[pos] = e;
        src_s[pos]  = src[e];
        dst_s[pos]  = d;
    }
}

// ---------------------------------------------------------------- pack [3][256][256] fp32 weights into MFMA B-frag hi/lo bf16
__global__ __launch_bounds__(256) void pack_w_kernel(const float* __restrict__ w,
                                                     unsigned short* __restrict__ whi,
                                                     unsigned short* __restrict__ wlo)
{
    const int f     = blockIdx.x;          // 0..383
    const int layer = f >> 7;
    const int rem   = f & 127;
    const int ntile = rem >> 3;
    const int k8    = rem & 7;
    for (int i = threadIdx.x; i < 512; i += 256){
        const int lane = i >> 3, j = i & 7;
        const int k = k8*32 + (lane >> 4)*8 + j;
        const int n = ntile*16 + (lane & 15);
        const float v = w[(size_t)layer*HID*HID + (size_t)k*HID + n];
        const unsigned short hb = f2bf(v);
        whi[(size_t)f*512 + i] = hb;
        wlo[(size_t)f*512 + i] = f2bf(v - bf2f(hb));
    }
}

// ---------------------------------------------------------------- layer-0 edge conv (C=92, fp32), sorted edges + run merge
__global__ __launch_bounds__(128) void edge_conv92_kernel(
    const int* __restrict__ perm_s, const int* __restrict__ src_s, const int* __restrict__ dst_s,
    const float* __restrict__ ea,
    const float* __restrict__ w1, const float* __restrict__ b1,
    const float* __restrict__ w2, const float* __restrict__ b2,
    const float* __restrict__ x, float* __restrict__ agg)
{
    constexpr int C = EMB_DIM;
    constexpr int EPB = 16;
    __shared__ float h1[EPB][C];
    const int win = xcd_window(N_EDGES/EPB);
    if (win < 0) return;
    const int e0  = win * EPB;
    const int tid = threadIdx.x;

    for (int idx = tid; idx < EPB*C; idx += 128){
        const int e = idx / C, k = idx - e*C;
        const float4 a = *(const float4*)(ea + (size_t)perm_s[e0+e]*4);
        float v = fmaf(a.x, w1[k], fmaf(a.y, w1[C+k], fmaf(a.z, w1[2*C+k], fmaf(a.w, w1[3*C+k], b1[k]))));
        h1[e][k] = softplusf(v);
    }
    __syncthreads();

    const int c = tid;
    if (c < C){
        float acc[EPB];
        #pragma unroll
        for (int e=0;e<EPB;e++) acc[e] = 0.0f;
        for (int k=0;k<C;k+=4){             // 92 = 23*4
            const float w0  = w2[(k+0)*C+c];
            const float w1v = w2[(k+1)*C+c];
            const float w2v = w2[(k+2)*C+c];
            const float w3v = w2[(k+3)*C+c];
            #pragma unroll
            for (int e=0;e<EPB;e++){
                const float4 hv = *(const float4*)&h1[e][k];
                acc[e] = fmaf(hv.x,w0,fmaf(hv.y,w1v,fmaf(hv.z,w2v,fmaf(hv.w,w3v,acc[e]))));
            }
        }
        const float bb = b2[c];
        int dprev = dst_s[e0];
        float run = 0.0f;
        #pragma unroll
        for (int e=0;e<EPB;e++){
            const int eid = e0 + e;
            const int s = src_s[eid], d = dst_s[eid];
            const float msg = (acc[e] + bb) * x[(size_t)s*C + c];
            if (d != dprev){
                atomicAdd(&agg[(size_t)dprev*C + c], run);
                run = 0.0f; dprev = d;
            }
            run += msg;
        }
        atomicAdd(&agg[(size_t)dprev*C + c], run);
    }
}

// ---------------------------------------------------------------- layers 1-3 edge conv, MFMA, 32 edges/block
// A = bf16(h1) single; B = w2 hi/lo (2 MFMA). LDS 17.9KB -> 8 blocks/CU.
__global__ __launch_bounds__(256, 8) void edge_conv256_mfma_kernel(
    const int* __restrict__ perm_s, const int* __restrict__ src_s, const int* __restrict__ dst_s,
    const float* __restrict__ ea,
    const float* __restrict__ w1, const float* __restrict__ b1,
    const unsigned short* __restrict__ whi, const unsigned short* __restrict__ wlo,
    const float* __restrict__ b2,
    const float* __restrict__ x, float* __restrict__ agg)
{
    constexpr int C = HID;
    constexpr int LDA = C + 8;                 // ushort row stride 528 B -> 2-way bank alias (free)
    constexpr int EPB = 32;
    __shared__ unsigned short aHi[EPB][LDA];   // 16.9 KB
    __shared__ float eaS[EPB][4];
    __shared__ int   srcS[EPB];
    __shared__ int   dstS[EPB];

    const int win = xcd_window(N_EDGES/EPB);   // 9375 windows
    if (win < 0) return;
    const int e0  = win * EPB;
    const int tid = threadIdx.x;

    // stage ea[perm], src, dst cooperatively
    if (tid < 128){
        const int e = tid >> 2, comp = tid & 3;
        eaS[e][comp] = ea[(size_t)perm_s[e0+e]*4 + comp];
    } else if (tid < 160){
        srcS[tid-128] = src_s[e0 + tid-128];
    } else if (tid < 192){
        dstS[tid-160] = dst_s[e0 + tid-160];
    }
    __syncthreads();

    // phase 1: h1 = softplus(ea@w1+b1) -> bf16 LDS (thread = channel)
    {
        const int k = tid;
        const float w10 = w1[k], w11 = w1[C+k], w12 = w1[2*C+k], w13 = w1[3*C+k];
        const float bk  = b1[k];
        #pragma unroll
        for (int e=0;e<EPB;e++){
            const float4 a = *(const float4*)&eaS[e][0];   // LDS broadcast
            const float v = fmaf(a.x,w10,fmaf(a.y,w11,fmaf(a.z,w12,fmaf(a.w,w13,bk))));
            aHi[e][k] = f2bf(softplusf(v));
        }
    }
    __syncthreads();

    const int lane = tid & 63, wv = tid >> 6;
    const int quad = lane >> 4, fcol = lane & 15;

    f32x4 acc[2][4];
    #pragma unroll
    for (int m=0;m<2;m++)
        #pragma unroll
        for (int t=0;t<4;t++)
            #pragma unroll
            for (int j=0;j<4;j++) acc[m][t][j] = 0.0f;

    for (int k8=0;k8<8;k8++){
        bf16x8 ah[2];
        #pragma unroll
        for (int m=0;m<2;m++)
            ah[m] = *(const bf16x8*)(&aHi[m*16 + fcol][0] + k8*32 + quad*8);
        #pragma unroll
        for (int t=0;t<4;t++){
            const int fi = (wv*4 + t)*8 + k8;
            const bf16x8 bh = *(const bf16x8*)(whi + (size_t)fi*512 + lane*8);
            const bf16x8 bl = *(const bf16x8*)(wlo + (size_t)fi*512 + lane*8);
            #pragma unroll
            for (int m=0;m<2;m++){
                acc[m][t] = __builtin_amdgcn_mfma_f32_16x16x32_bf16(ah[m], bh, acc[m][t], 0, 0, 0);
                acc[m][t] = __builtin_amdgcn_mfma_f32_16x16x32_bf16(ah[m], bl, acc[m][t], 0, 0, 0);
            }
        }
    }

    // epilogue: C/D layout col = lane&15 (n), row = quad*4 + reg (edge); run-merge sorted dsts
    float bb[4];
    #pragma unroll
    for (int t=0;t<4;t++) bb[t] = b2[(wv*4 + t)*16 + fcol];

    #pragma unroll
    for (int m=0;m<2;m++){
        const int ebase = m*16 + quad*4;
        int dprev = dstS[ebase];
        float run[4] = {0.f,0.f,0.f,0.f};
        #pragma unroll
        for (int i=0;i<4;i++){
            const int s = srcS[ebase+i], d = dstS[ebase+i];
            if (d != dprev){
                #pragma unroll
                for (int t=0;t<4;t++){
                    const int n = (wv*4 + t)*16 + fcol;
                    atomicAdd(&agg[(size_t)dprev*C + n], run[t]);
                    run[t] = 0.0f;
                }
                dprev = d;
            }
            #pragma unroll
            for (int t=0;t<4;t++){
                const int n = (wv*4 + t)*16 + fcol;
                run[t] += (acc[m][t][i] + bb[t]) * x[(size_t)s*C + n];
            }
        }
        #pragma unroll
        for (int t=0;t<4;t++){
            const int n = (wv*4 + t)*16 + fcol;
            atomicAdd(&agg[(size_t)dprev*C + n], run[t]);
        }
    }
}

// ---------------------------------------------------------------- node update MFMA (CIN=256): x = softplus(agg @ nw + nb)
__global__ __launch_bounds__(256) void node_update_mfma_kernel(
    const float* __restrict__ agg,
    const unsigned short* __restrict__ whi, const unsigned short* __restrict__ wlo,
    const float* __restrict__ b, float* __restrict__ xout)
{
    constexpr int C = HID;
    constexpr int LDA = C + 8;
    __shared__ unsigned short aHi[16][LDA];
    __shared__ unsigned short aLo[16][LDA];

    const int n0  = blockIdx.x * 16;
    const int tid = threadIdx.x;

    #pragma unroll
    for (int it=0; it<16; it++){
        const int node = n0 + it;
        const float v = (node < N_NODES) ? agg[(size_t)node*C + tid] : 0.0f;
        unsigned short hb, lb;
        split_bf(v, hb, lb);
        aHi[it][tid] = hb;
        aLo[it][tid] = lb;
    }
    __syncthreads();

    const int lane = tid & 63, wv = tid >> 6;
    const int quad = lane >> 4, fcol = lane & 15;

    f32x4 acc[4];
    #pragma unroll
    for (int t=0;t<4;t++)
        #pragma unroll
        for (int j=0;j<4;j++) acc[t][j] = 0.0f;

    const unsigned short* aHrow = &aHi[fcol][0];
    const unsigned short* aLrow = &aLo[fcol][0];

    for (int k8=0;k8<8;k8++){
        const bf16x8 ah = *(const bf16x8*)(aHrow + k8*32 + quad*8);
        const bf16x8 al = *(const bf16x8*)(aLrow + k8*32 + quad*8);
        #pragma unroll
        for (int t=0;t<4;t++){
            const int fi = (wv*4 + t)*8 + k8;
            const bf16x8 bh = *(const bf16x8*)(whi + (size_t)fi*512 + lane*8);
            const bf16x8 bl = *(const bf16x8*)(wlo + (size_t)fi*512 + lane*8);
            acc[t] = __builtin_amdgcn_mfma_f32_16x16x32_bf16(ah, bh, acc[t], 0, 0, 0);
            acc[t] = __builtin_amdgcn_mfma_f32_16x16x32_bf16(ah, bl, acc[t], 0, 0, 0);
            acc[t] = __builtin_amdgcn_mfma_f32_16x16x32_bf16(al, bh, acc[t], 0, 0, 0);
        }
    }

    #pragma unroll
    for (int i=0;i<4;i++){
        const int node = n0 + quad*4 + i;
        if (node < N_NODES){
            #pragma unroll
            for (int t=0;t<4;t++){
                const int n = (wv*4 + t)*16 + fcol;
                xout[(size_t)node*C + n] = softplusf(acc[t][i] + b[n]);
            }
        }
    }
}

// ---------------------------------------------------------------- node update fp32 (layer 0, CIN=92)
__global__ __launch_bounds__(256) void node_update92_kernel(
    const float* __restrict__ agg, const float* __restrict__ w,
    const float* __restrict__ b, float* __restrict__ xout)
{
    constexpr int CIN = EMB_DIM, NPB = 4;
    __shared__ float row[NPB][CIN];
    const int n0 = blockIdx.x * NPB;
    for (int idx = threadIdx.x; idx < NPB*CIN; idx += 256){
        const int i = idx / CIN, k = idx - i*CIN;
        row[i][k] = agg[(size_t)(n0+i)*CIN + k];
    }
    __syncthreads();
    const int c = threadIdx.x;
    float acc[NPB];
    #pragma unroll
    for (int i=0;i<NPB;i++) acc[i] = b[c];
    for (int k=0;k<CIN;k+=4){
        const float w0  = w[(k+0)*HID+c];
        const float w1v = w[(k+1)*HID+c];
        const float w2v = w[(k+2)*HID+c];
        const float w3v = w[(k+3)*HID+c];
        #pragma unroll
        for (int i=0;i<NPB;i++){
            const float4 r = *(const float4*)&row[i][k];
            acc[i] = fmaf(r.x,w0,fmaf(r.y,w1v,fmaf(r.z,w2v,fmaf(r.w,w3v,acc[i]))));
        }
    }
    #pragma unroll
    for (int i=0;i<NPB;i++)
        xout[(size_t)(n0+i)*HID + c] = softplusf(acc[i]);
}

// ---------------------------------------------------------------- mean pool, run-merged (batch is sorted)
__global__ __launch_bounds__(256) void pool_kernel(
    const float* __restrict__ x, const int* __restrict__ batch,
    float* __restrict__ sums, float* __restrict__ cnts)
{
    constexpr int NPB = 32;
    const int n0 = blockIdx.x * NPB;
    const int c  = threadIdx.x;
    int gprev = batch[n0];
    float run = 0.0f, crun = 0.0f;
    for (int i=0;i<NPB;i++){
        const int n = n0 + i;
        if (n >= N_NODES) break;
        const int g = batch[n];
        if (g != gprev){
            atomicAdd(&sums[(size_t)gprev*HID + c], run);
            if (c == 0) atomicAdd(&cnts[gprev], crun);
            run = 0.0f; crun = 0.0f; gprev = g;
        }
        run  += x[(size_t)n*HID + c];
        crun += 1.0f;
    }
    atomicAdd(&sums[(size_t)gprev*HID + c], run);
    if (c == 0) atomicAdd(&cnts[gprev], crun);
}

// ---------------------------------------------------------------- readout MLP (one block per graph)
__global__ __launch_bounds__(256) void readout_kernel(
    const float* __restrict__ sums, const float* __restrict__ cnts,
    const float* __restrict__ rw1, const float* __restrict__ rb1,
    const float* __restrict__ rw2, const float* __restrict__ rb2,
    const float* __restrict__ rw3, const float* __restrict__ rb3,
    float* __restrict__ out)
{
    __shared__ float g[HID];
    __shared__ float h[HID];
    __shared__ float h2[HID/2];
    __shared__ float red[256];
    const int gi = blockIdx.x;
    const int t  = threadIdx.x;
    const float cnt = fmaxf(cnts[gi], 1.0f);
    g[t] = sums[(size_t)gi*HID + t] / cnt;
    __syncthreads();
    float acc = rb1[t];
    for (int k=0;k<HID;k++) acc = fmaf(g[k], rw1[(size_t)k*HID + t], acc);
    h[t] = softplusf(acc);
    __syncthreads();
    if (t < HID/2){
        float a2 = rb2[t];
        for (int k=0;k<HID;k++) a2 = fmaf(h[k], rw2[(size_t)k*(HID/2) + t], a2);
        h2[t] = softplusf(a2);
    }
    __syncthreads();
    red[t] = (t < HID/2) ? h2[t]*rw3[t] : 0.0f;
    __syncthreads();
    for (int s2=128; s2>0; s2>>=1){
        if (t < s2) red[t] += red[t+s2];
        __syncthreads();
    }
    if (t == 0) out[gi] = red[0] + rb3[0];
}

// ---------------------------------------------------------------- launcher
extern "C" void kernel_launch(void* const* d_in, const int* in_sizes, int n_in,
                              void* d_out, int out_size, void* d_ws, size_t ws_size,
                              hipStream_t stream)
{
    const int*   x_atoms = (const int*)d_in[0];
    const int*   eidx    = (const int*)d_in[1];
    const int*   src     = eidx;               // edge_index[0]
    const int*   dst     = eidx + N_EDGES;     // edge_index[1]
    const float* ea      = (const float*)d_in[2];
    const int*   batch   = (const int*)d_in[3];
    const float* emb     = (const float*)d_in[4];
    const float* ew1_0   = (const float*)d_in[5];
    const float* eb1_0   = (const float*)d_in[6];
    const float* ew2_0   = (const float*)d_in[7];
    const float* eb2_0   = (const float*)d_in[8];
    const float* nw_0    = (const float*)d_in[9];
    const float* nb_0    = (const float*)d_in[10];
    const float* ew1     = (const float*)d_in[11];
    const float* eb1     = (const float*)d_in[12];
    const float* ew2     = (const float*)d_in[13];
    const float* eb2     = (const float*)d_in[14];
    const float* nw      = (const float*)d_in[15];
    const float* nb      = (const float*)d_in[16];
    const float* rw1     = (const float*)d_in[17];
    const float* rb1     = (const float*)d_in[18];
    const float* rw2     = (const float*)d_in[19];
    const float* rb2     = (const float*)d_in[20];
    const float* rw3     = (const float*)d_in[21];
    const float* rb3     = (const float*)d_in[22];
    float* out = (float*)d_out;

    float* x    = (float*)d_ws;
    float* agg  = x   + (size_t)N_NODES*HID;
    float* sums = agg + (size_t)N_NODES*HID;
    float* cnts = sums + (size_t)N_GRAPHS*HID;
    unsigned short* whi  = (unsigned short*)(cnts + N_GRAPHS);
    unsigned short* wlo  = whi  + (size_t)3*128*512;
    unsigned short* nwhi = wlo  + (size_t)3*128*512;
    unsigned short* nwlo = nwhi + (size_t)3*128*512;
    int* hist   = (int*)(nwlo + (size_t)3*128*512);
    int* cursor = hist   + N_NODES;
    int* perm_s = cursor + N_NODES;
    int* src_s  = perm_s + N_EDGES;
    int* dst_s  = src_s  + N_EDGES;

    // ---- counting sort of edges by dst (once per launch) ----
    hipMemsetAsync(hist, 0, N_NODES*sizeof(int), stream);
    hipLaunchKernelGGL(hist_kernel, dim3((N_EDGES+255)/256), dim3(256), 0, stream, dst, hist);
    hipLaunchKernelGGL(scan_kernel, dim3(1), dim3(1024), 0, stream, hist, cursor);
    hipLaunchKernelGGL(scatter_kernel, dim3((N_EDGES+255)/256), dim3(256), 0, stream,
                       src, dst, cursor, perm_s, src_s, dst_s);

    // ---- pack weights for MFMA ----
    hipLaunchKernelGGL(pack_w_kernel, dim3(384), dim3(256), 0, stream, ew2, whi, wlo);
    hipLaunchKernelGGL(pack_w_kernel, dim3(384), dim3(256), 0, stream, nw, nwhi, nwlo);

    // ---- layer 0 (C = 92) ----
    hipLaunchKernelGGL(gather_emb_kernel, dim3(N_NODES), dim3(128), 0, stream, x_atoms, emb, x);
    hipMemsetAsync(agg, 0, (size_t)N_NODES*EMB_DIM*sizeof(float), stream);
    hipLaunchKernelGGL(edge_conv92_kernel, dim3(((N_EDGES/16)+7)/8*8), dim3(128), 0, stream,
                       perm_s, src_s, dst_s, ea, ew1_0, eb1_0, ew2_0, eb2_0, x, agg);
    hipLaunchKernelGGL(node_update92_kernel, dim3(N_NODES/4), dim3(256), 0, stream,
                       agg, nw_0, nb_0, x);

    // ---- layers 1..3 (C = 256), MFMA ----
    for (int i=0;i<3;i++){
        hipMemsetAsync(agg, 0, (size_t)N_NODES*HID*sizeof(float), stream);
        hipLaunchKernelGGL(edge_conv256_mfma_kernel, dim3(((N_EDGES/32)+7)/8*8), dim3(256), 0, stream,
                           perm_s, src_s, dst_s, ea,
                           ew1 + (size_t)i*4*HID, eb1 + (size_t)i*HID,
                           whi + (size_t)i*128*512, wlo + (size_t)i*128*512,
                           eb2 + (size_t)i*HID,
                           x, agg);
        hipLaunchKernelGGL(node_update_mfma_kernel, dim3((N_NODES+15)/16), dim3(256), 0, stream,
                           agg, nwhi + (size_t)i*128*512, nwlo + (size_t)i*128*512,
                           nb + (size_t)i*HID, x);
    }

    // ---- pool + readout ----
    hipMemsetAsync(sums, 0, ((size_t)N_GRAPHS*HID + N_GRAPHS)*sizeof(float), stream);
    hipLaunchKernelGGL(pool_kernel, dim3((N_NODES+31)/32), dim3(256), 0, stream, x, batch, sums, cnts);
    hipLaunchKernelGGL(readout_kernel, dim3(N_GRAPHS), dim3(256), 0, stream,
                       sums, cnts, rw1, rb1, rw2, rb2, rw3, rb3, out);
}

// Round 8
// 970.237 us; speedup vs baseline: 1.3013x; 1.3013x over previous
//
#include <hip/hip_runtime.h>
#include <math.h>

#define N_NODES  25000
#define N_EDGES  300000
#define N_GRAPHS 256
#define EMB_DIM  92
#define HID      256

typedef short bf16x8 __attribute__((ext_vector_type(8)));
typedef float f32x4  __attribute__((ext_vector_type(4)));

// fast softplus == jax.nn.softplus to ~1e-6 abs
__device__ __forceinline__ float softplusf(float x){
    return fmaxf(x, 0.0f) + __logf(1.0f + __expf(-fabsf(x)));
}
__device__ __forceinline__ unsigned short f2bf(float f){
    unsigned int u = __float_as_uint(f);
    unsigned int r = (u + 0x7FFFu + ((u >> 16) & 1u)) >> 16;   // RNE
    return (unsigned short)r;
}
__device__ __forceinline__ float bf2f(unsigned short b){
    return __uint_as_float(((unsigned int)b) << 16);
}
// truncation hi/lo split (used for node-update A operand; 3-MFMA scheme)
__device__ __forceinline__ void split_bf(float h, unsigned short& hi, unsigned short& lo){
    const unsigned int u = __float_as_uint(h);
    hi = (unsigned short)(u >> 16);
    const float r = h - __uint_as_float(u & 0xFFFF0000u);
    lo = (unsigned short)(__float_as_uint(r) >> 16);
}
// XCD-contiguity swizzle (neutral so far; kept — harmless, may matter once latency-fixed)
__device__ __forceinline__ int xcd_window(int nwin){
    const int per = (nwin + 7) >> 3;
    const int win = (blockIdx.x & 7) * per + (blockIdx.x >> 3);
    return (win < nwin) ? win : -1;
}

// ---------------------------------------------------------------- embedding gather
__global__ void gather_emb_kernel(const int* __restrict__ atoms,
                                  const float* __restrict__ emb,
                                  float* __restrict__ x)
{
    const int n = blockIdx.x;
    const int c = threadIdx.x;
    if (c < EMB_DIM){
        const int a = atoms[n];
        x[(size_t)n*EMB_DIM + c] = emb[(size_t)a*EMB_DIM + c];
    }
}

// ---------------------------------------------------------------- counting sort by dst
__global__ __launch_bounds__(256) void hist_kernel(const int* __restrict__ dst, int* __restrict__ hist){
    const int e = blockIdx.x*256 + threadIdx.x;
    if (e < N_EDGES) atomicAdd(&hist[dst[e]], 1);
}

__global__ __launch_bounds__(1024) void scan_kernel(const int* __restrict__ hist, int* __restrict__ cursor){
    __shared__ int chunk[1024];
    const int t = threadIdx.x;
    const int base = t*25;                     // 1024*25 = 25600 >= 25000
    int local[25];
    int s = 0;
    #pragma unroll
    for (int i=0;i<25;i++){
        const int idx = base+i;
        const int v = (idx < N_NODES) ? hist[idx] : 0;
        local[i] = s; s += v;
    }
    chunk[t] = s;
    __syncthreads();
    for (int off=1; off<1024; off<<=1){
        int v = (t >= off) ? chunk[t-off] : 0;
        __syncthreads();
        chunk[t] += v;
        __syncthreads();
    }
    const int pre = (t > 0) ? chunk[t-1] : 0;
    #pragma unroll
    for (int i=0;i<25;i++){
        const int idx = base+i;
        if (idx < N_NODES) cursor[idx] = pre + local[i];
    }
}

__global__ __launch_bounds__(256) void scatter_kernel(const int* __restrict__ src, const int* __restrict__ dst,
                                                      int* __restrict__ cursor,
                                                      int* __restrict__ perm_s, int* __restrict__ src_s,
                                                      int* __restrict__ dst_s){
    const int e = blockIdx.x*256 + threadIdx.x;
    if (e < N_EDGES){
        const int d = dst[e];
        const int pos = atomicAdd(&cursor[d], 1);
        perm_s[pos] = e;
        src_s[pos]  = src[e];
        dst_s[pos]  = d;
    }
}

// ---------------------------------------------------------------- pack [3][256][256] fp32 weights into MFMA B-frag hi/lo bf16
__global__ __launch_bounds__(256) void pack_w_kernel(const float* __restrict__ w,
                                                     unsigned short* __restrict__ whi,
                                                     unsigned short* __restrict__ wlo)
{
    const int f     = blockIdx.x;          // 0..383
    const int layer = f >> 7;
    const int rem   = f & 127;
    const int ntile = rem >> 3;
    const int k8    = rem & 7;
    for (int i = threadIdx.x; i < 512; i += 256){
        const int lane = i >> 3, j = i & 7;
        const int k = k8*32 + (lane >> 4)*8 + j;
        const int n = ntile*16 + (lane & 15);
        const float v = w[(size_t)layer*HID*HID + (size_t)k*HID + n];
        const unsigned short hb = f2bf(v);
        whi[(size_t)f*512 + i] = hb;
        wlo[(size_t)f*512 + i] = f2bf(v - bf2f(hb));
    }
}

// ---------------------------------------------------------------- layer-0 edge conv (C=92, fp32), sorted edges + run merge
__global__ __launch_bounds__(128) void edge_conv92_kernel(
    const int* __restrict__ perm_s, const int* __restrict__ src_s, const int* __restrict__ dst_s,
    const float* __restrict__ ea,
    const float* __restrict__ w1, const float* __restrict__ b1,
    const float* __restrict__ w2, const float* __restrict__ b2,
    const float* __restrict__ x, float* __restrict__ agg)
{
    constexpr int C = EMB_DIM;
    constexpr int EPB = 16;
    __shared__ float h1[EPB][C];
    const int win = xcd_window(N_EDGES/EPB);
    if (win < 0) return;
    const int e0  = win * EPB;
    const int tid = threadIdx.x;

    for (int idx = tid; idx < EPB*C; idx += 128){
        const int e = idx / C, k = idx - e*C;
        const float4 a = *(const float4*)(ea + (size_t)perm_s[e0+e]*4);
        float v = fmaf(a.x, w1[k], fmaf(a.y, w1[C+k], fmaf(a.z, w1[2*C+k], fmaf(a.w, w1[3*C+k], b1[k]))));
        h1[e][k] = softplusf(v);
    }
    __syncthreads();

    const int c = tid;
    if (c < C){
        float acc[EPB];
        #pragma unroll
        for (int e=0;e<EPB;e++) acc[e] = 0.0f;
        for (int k=0;k<C;k+=4){             // 92 = 23*4
            const float w0  = w2[(k+0)*C+c];
            const float w1v = w2[(k+1)*C+c];
            const float w2v = w2[(k+2)*C+c];
            const float w3v = w2[(k+3)*C+c];
            #pragma unroll
            for (int e=0;e<EPB;e++){
                const float4 hv = *(const float4*)&h1[e][k];
                acc[e] = fmaf(hv.x,w0,fmaf(hv.y,w1v,fmaf(hv.z,w2v,fmaf(hv.w,w3v,acc[e]))));
            }
        }
        const float bb = b2[c];
        int dprev = dst_s[e0];
        float run = 0.0f;
        #pragma unroll
        for (int e=0;e<EPB;e++){
            const int eid = e0 + e;
            const int s = src_s[eid], d = dst_s[eid];
            const float msg = (acc[e] + bb) * x[(size_t)s*C + c];
            if (d != dprev){
                atomicAdd(&agg[(size_t)dprev*C + c], run);
                run = 0.0f; dprev = d;
            }
            run += msg;
        }
        atomicAdd(&agg[(size_t)dprev*C + c], run);
    }
}

// ---------------------------------------------------------------- layers 1-3 edge conv, MFMA, 32 edges/block
// A = bf16(h1); B = w2 hi/lo (2 MFMA). Window edge e = q*8 + m*4 + i lives in
// MFMA row m*16 + q*4 + i, so each quad owns one CONTIGUOUS 8-edge dst-sorted
// chain (m0 regs then m1 regs) -> longer run-merge, ~1.6x fewer atomics.
// __launch_bounds__(256,4): 128 VGPR budget so B-frags + 32 x-gathers stay in flight.
__global__ __launch_bounds__(256, 4) void edge_conv256_mfma_kernel(
    const int* __restrict__ perm_s, const int* __restrict__ src_s, const int* __restrict__ dst_s,
    const float* __restrict__ ea,
    const float* __restrict__ w1, const float* __restrict__ b1,
    const unsigned short* __restrict__ whi, const unsigned short* __restrict__ wlo,
    const float* __restrict__ b2,
    const float* __restrict__ x, float* __restrict__ agg)
{
    constexpr int C = HID;
    constexpr int LDA = C + 8;                 // ushort row stride 528 B -> 2-way bank alias (free)
    constexpr int EPB = 32;
    __shared__ unsigned short aHi[EPB][LDA];   // 16.9 KB
    __shared__ float eaS[EPB][4];
    __shared__ int   srcS[EPB];
    __shared__ int   dstS[EPB];

    const int win = xcd_window(N_EDGES/EPB);   // 9375 windows
    if (win < 0) return;
    const int e0  = win * EPB;
    const int tid = threadIdx.x;

    // stage ea[perm], src, dst cooperatively
    if (tid < 128){
        const int e = tid >> 2, comp = tid & 3;
        eaS[e][comp] = ea[(size_t)perm_s[e0+e]*4 + comp];
    } else if (tid < 160){
        srcS[tid-128] = src_s[e0 + tid-128];
    } else if (tid < 192){
        dstS[tid-160] = dst_s[e0 + tid-160];
    }
    __syncthreads();

    // phase 1: h1 = softplus(ea@w1+b1) -> bf16 LDS rows permuted per chain map
    {
        const int k = tid;
        const float w10 = w1[k], w11 = w1[C+k], w12 = w1[2*C+k], w13 = w1[3*C+k];
        const float bk  = b1[k];
        #pragma unroll
        for (int e=0;e<EPB;e++){
            const float4 a = *(const float4*)&eaS[e][0];   // LDS broadcast
            const float v = fmaf(a.x,w10,fmaf(a.y,w11,fmaf(a.z,w12,fmaf(a.w,w13,bk))));
            const int q = e >> 3, m = (e >> 2) & 1, i = e & 3;
            aHi[m*16 + q*4 + i][k] = f2bf(softplusf(v));
        }
    }
    __syncthreads();

    const int lane = tid & 63, wv = tid >> 6;
    const int quad = lane >> 4, fcol = lane & 15;

    f32x4 acc[2][4];
    #pragma unroll
    for (int m=0;m<2;m++)
        #pragma unroll
        for (int t=0;t<4;t++)
            #pragma unroll
            for (int j=0;j<4;j++) acc[m][t][j] = 0.0f;

    for (int k8=0;k8<8;k8++){
        bf16x8 ah[2];
        #pragma unroll
        for (int m=0;m<2;m++)
            ah[m] = *(const bf16x8*)(&aHi[m*16 + fcol][0] + k8*32 + quad*8);
        #pragma unroll
        for (int t=0;t<4;t++){
            const int fi = (wv*4 + t)*8 + k8;
            const bf16x8 bh = *(const bf16x8*)(whi + (size_t)fi*512 + lane*8);
            const bf16x8 bl = *(const bf16x8*)(wlo + (size_t)fi*512 + lane*8);
            #pragma unroll
            for (int m=0;m<2;m++){
                acc[m][t] = __builtin_amdgcn_mfma_f32_16x16x32_bf16(ah[m], bh, acc[m][t], 0, 0, 0);
                acc[m][t] = __builtin_amdgcn_mfma_f32_16x16x32_bf16(ah[m], bl, acc[m][t], 0, 0, 0);
            }
        }
    }

    // epilogue: quad q owns edges q*8..q*8+7 (value for j: acc[j>>2][t][j&3]).
    // Hoist all 32 x-gathers into regs (keeps loads in flight), then run-merge.
    float bb[4];
    #pragma unroll
    for (int t=0;t<4;t++) bb[t] = b2[(wv*4 + t)*16 + fcol];

    const int ebase = quad*8;
    float xv[8][4];
    #pragma unroll
    for (int j=0;j<8;j++){
        const int s = srcS[ebase + j];
        #pragma unroll
        for (int t=0;t<4;t++)
            xv[j][t] = x[(size_t)s*C + (wv*4 + t)*16 + fcol];
    }

    int dprev = dstS[ebase];
    float run[4] = {0.f,0.f,0.f,0.f};
    #pragma unroll
    for (int j=0;j<8;j++){
        const int d = dstS[ebase + j];
        if (d != dprev){
            #pragma unroll
            for (int t=0;t<4;t++){
                atomicAdd(&agg[(size_t)dprev*C + (wv*4 + t)*16 + fcol], run[t]);
                run[t] = 0.0f;
            }
            dprev = d;
        }
        const int m = j >> 2, i = j & 3;
        #pragma unroll
        for (int t=0;t<4;t++)
            run[t] += (acc[m][t][i] + bb[t]) * xv[j][t];
    }
    #pragma unroll
    for (int t=0;t<4;t++)
        atomicAdd(&agg[(size_t)dprev*C + (wv*4 + t)*16 + fcol], run[t]);
}

// ---------------------------------------------------------------- node update MFMA (CIN=256): x = softplus(agg @ nw + nb)
__global__ __launch_bounds__(256) void node_update_mfma_kernel(
    const float* __restrict__ agg,
    const unsigned short* __restrict__ whi, const unsigned short* __restrict__ wlo,
    const float* __restrict__ b, float* __restrict__ xout)
{
    constexpr int C = HID;
    constexpr int LDA = C + 8;
    __shared__ unsigned short aHi[16][LDA];
    __shared__ unsigned short aLo[16][LDA];

    const int n0  = blockIdx.x * 16;
    const int tid = threadIdx.x;

    #pragma unroll
    for (int it=0; it<16; it++){
        const int node = n0 + it;
        const float v = (node < N_NODES) ? agg[(size_t)node*C + tid] : 0.0f;
        unsigned short hb, lb;
        split_bf(v, hb, lb);
        aHi[it][tid] = hb;
        aLo[it][tid] = lb;
    }
    __syncthreads();

    const int lane = tid & 63, wv = tid >> 6;
    const int quad = lane >> 4, fcol = lane & 15;

    f32x4 acc[4];
    #pragma unroll
    for (int t=0;t<4;t++)
        #pragma unroll
        for (int j=0;j<4;j++) acc[t][j] = 0.0f;

    const unsigned short* aHrow = &aHi[fcol][0];
    const unsigned short* aLrow = &aLo[fcol][0];

    for (int k8=0;k8<8;k8++){
        const bf16x8 ah = *(const bf16x8*)(aHrow + k8*32 + quad*8);
        const bf16x8 al = *(const bf16x8*)(aLrow + k8*32 + quad*8);
        #pragma unroll
        for (int t=0;t<4;t++){
            const int fi = (wv*4 + t)*8 + k8;
            const bf16x8 bh = *(const bf16x8*)(whi + (size_t)fi*512 + lane*8);
            const bf16x8 bl = *(const bf16x8*)(wlo + (size_t)fi*512 + lane*8);
            acc[t] = __builtin_amdgcn_mfma_f32_16x16x32_bf16(ah, bh, acc[t], 0, 0, 0);
            acc[t] = __builtin_amdgcn_mfma_f32_16x16x32_bf16(ah, bl, acc[t], 0, 0, 0);
            acc[t] = __builtin_amdgcn_mfma_f32_16x16x32_bf16(al, bh, acc[t], 0, 0, 0);
        }
    }

    #pragma unroll
    for (int i=0;i<4;i++){
        const int node = n0 + quad*4 + i;
        if (node < N_NODES){
            #pragma unroll
            for (int t=0;t<4;t++){
                const int n = (wv*4 + t)*16 + fcol;
                xout[(size_t)node*C + n] = softplusf(acc[t][i] + b[n]);
            }
        }
    }
}

// ---------------------------------------------------------------- node update fp32 (layer 0, CIN=92)
__global__ __launch_bounds__(256) void node_update92_kernel(
    const float* __restrict__ agg, const float* __restrict__ w,
    const float* __restrict__ b, float* __restrict__ xout)
{
    constexpr int CIN = EMB_DIM, NPB = 4;
    __shared__ float row[NPB][CIN];
    const int n0 = blockIdx.x * NPB;
    for (int idx = threadIdx.x; idx < NPB*CIN; idx += 256){
        const int i = idx / CIN, k = idx - i*CIN;
        row[i][k] = agg[(size_t)(n0+i)*CIN + k];
    }
    __syncthreads();
    const int c = threadIdx.x;
    float acc[NPB];
    #pragma unroll
    for (int i=0;i<NPB;i++) acc[i] = b[c];
    for (int k=0;k<CIN;k+=4){
        const float w0  = w[(k+0)*HID+c];
        const float w1v = w[(k+1)*HID+c];
        const float w2v = w[(k+2)*HID+c];
        const float w3v = w[(k+3)*HID+c];
        #pragma unroll
        for (int i=0;i<NPB;i++){
            const float4 r = *(const float4*)&row[i][k];
            acc[i] = fmaf(r.x,w0,fmaf(r.y,w1v,fmaf(r.z,w2v,fmaf(r.w,w3v,acc[i]))));
        }
    }
    #pragma unroll
    for (int i=0;i<NPB;i++)
        xout[(size_t)(n0+i)*HID + c] = softplusf(acc[i]);
}

// ---------------------------------------------------------------- mean pool, run-merged (batch is sorted)
__global__ __launch_bounds__(256) void pool_kernel(
    const float* __restrict__ x, const int* __restrict__ batch,
    float* __restrict__ sums, float* __restrict__ cnts)
{
    constexpr int NPB = 32;
    const int n0 = blockIdx.x * NPB;
    const int c  = threadIdx.x;
    int gprev = batch[n0];
    float run = 0.0f, crun = 0.0f;
    for (int i=0;i<NPB;i++){
        const int n = n0 + i;
        if (n >= N_NODES) break;
        const int g = batch[n];
        if (g != gprev){
            atomicAdd(&sums[(size_t)gprev*HID + c], run);
            if (c == 0) atomicAdd(&cnts[gprev], crun);
            run = 0.0f; crun = 0.0f; gprev = g;
        }
        run  += x[(size_t)n*HID + c];
        crun += 1.0f;
    }
    atomicAdd(&sums[(size_t)gprev*HID + c], run);
    if (c == 0) atomicAdd(&cnts[gprev], crun);
}

// ---------------------------------------------------------------- readout MLP (one block per graph)
__global__ __launch_bounds__(256) void readout_kernel(
    const float* __restrict__ sums, const float* __restrict__ cnts,
    const float* __restrict__ rw1, const float* __restrict__ rb1,
    const float* __restrict__ rw2, const float* __restrict__ rb2,
    const float* __restrict__ rw3, const float* __restrict__ rb3,
    float* __restrict__ out)
{
    __shared__ float g[HID];
    __shared__ float h[HID];
    __shared__ float h2[HID/2];
    __shared__ float red[256];
    const int gi = blockIdx.x;
    const int t  = threadIdx.x;
    const float cnt = fmaxf(cnts[gi], 1.0f);
    g[t] = sums[(size_t)gi*HID + t] / cnt;
    __syncthreads();
    float acc = rb1[t];
    for (int k=0;k<HID;k++) acc = fmaf(g[k], rw1[(size_t)k*HID + t], acc);
    h[t] = softplusf(acc);
    __syncthreads();
    if (t < HID/2){
        float a2 = rb2[t];
        for (int k=0;k<HID;k++) a2 = fmaf(h[k], rw2[(size_t)k*(HID/2) + t], a2);
        h2[t] = softplusf(a2);
    }
    __syncthreads();
    red[t] = (t < HID/2) ? h2[t]*rw3[t] : 0.0f;
    __syncthreads();
    for (int s2=128; s2>0; s2>>=1){
        if (t < s2) red[t] += red[t+s2];
        __syncthreads();
    }
    if (t == 0) out[gi] = red[0] + rb3[0];
}

// ---------------------------------------------------------------- launcher
extern "C" void kernel_launch(void* const* d_in, const int* in_sizes, int n_in,
                              void* d_out, int out_size, void* d_ws, size_t ws_size,
                              hipStream_t stream)
{
    const int*   x_atoms = (const int*)d_in[0];
    const int*   eidx    = (const int*)d_in[1];
    const int*   src     = eidx;               // edge_index[0]
    const int*   dst     = eidx + N_EDGES;     // edge_index[1]
    const float* ea      = (const float*)d_in[2];
    const int*   batch   = (const int*)d_in[3];
    const float* emb     = (const float*)d_in[4];
    const float* ew1_0   = (const float*)d_in[5];
    const float* eb1_0   = (const float*)d_in[6];
    const float* ew2_0   = (const float*)d_in[7];
    const float* eb2_0   = (const float*)d_in[8];
    const float* nw_0    = (const float*)d_in[9];
    const float* nb_0    = (const float*)d_in[10];
    const float* ew1     = (const float*)d_in[11];
    const float* eb1     = (const float*)d_in[12];
    const float* ew2     = (const float*)d_in[13];
    const float* eb2     = (const float*)d_in[14];
    const float* nw      = (const float*)d_in[15];
    const float* nb      = (const float*)d_in[16];
    const float* rw1     = (const float*)d_in[17];
    const float* rb1     = (const float*)d_in[18];
    const float* rw2     = (const float*)d_in[19];
    const float* rb2     = (const float*)d_in[20];
    const float* rw3     = (const float*)d_in[21];
    const float* rb3     = (const float*)d_in[22];
    float* out = (float*)d_out;

    float* x    = (float*)d_ws;
    float* agg  = x   + (size_t)N_NODES*HID;
    float* sums = agg + (size_t)N_NODES*HID;
    float* cnts = sums + (size_t)N_GRAPHS*HID;
    unsigned short* whi  = (unsigned short*)(cnts + N_GRAPHS);
    unsigned short* wlo  = whi  + (size_t)3*128*512;
    unsigned short* nwhi = wlo  + (size_t)3*128*512;
    unsigned short* nwlo = nwhi + (size_t)3*128*512;
    int* hist   = (int*)(nwlo + (size_t)3*128*512);
    int* cursor = hist   + N_NODES;
    int* perm_s = cursor + N_NODES;
    int* src_s  = perm_s + N_EDGES;
    int* dst_s  = src_s  + N_EDGES;

    // ---- counting sort of edges by dst (once per launch) ----
    hipMemsetAsync(hist, 0, N_NODES*sizeof(int), stream);
    hipLaunchKernelGGL(hist_kernel, dim3((N_EDGES+255)/256), dim3(256), 0, stream, dst, hist);
    hipLaunchKernelGGL(scan_kernel, dim3(1), dim3(1024), 0, stream, hist, cursor);
    hipLaunchKernelGGL(scatter_kernel, dim3((N_EDGES+255)/256), dim3(256), 0, stream,
                       src, dst, cursor, perm_s, src_s, dst_s);

    // ---- pack weights for MFMA ----
    hipLaunchKernelGGL(pack_w_kernel, dim3(384), dim3(256), 0, stream, ew2, whi, wlo);
    hipLaunchKernelGGL(pack_w_kernel, dim3(384), dim3(256), 0, stream, nw, nwhi, nwlo);

    // ---- layer 0 (C = 92) ----
    hipLaunchKernelGGL(gather_emb_kernel, dim3(N_NODES), dim3(128), 0, stream, x_atoms, emb, x);
    hipMemsetAsync(agg, 0, (size_t)N_NODES*EMB_DIM*sizeof(float), stream);
    hipLaunchKernelGGL(edge_conv92_kernel, dim3(((N_EDGES/16)+7)/8*8), dim3(128), 0, stream,
                       perm_s, src_s, dst_s, ea, ew1_0, eb1_0, ew2_0, eb2_0, x, agg);
    hipLaunchKernelGGL(node_update92_kernel, dim3(N_NODES/4), dim3(256), 0, stream,
                       agg, nw_0, nb_0, x);

    // ---- layers 1..3 (C = 256), MFMA ----
    for (int i=0;i<3;i++){
        hipMemsetAsync(agg, 0, (size_t)N_NODES*HID*sizeof(float), stream);
        hipLaunchKernelGGL(edge_conv256_mfma_kernel, dim3(((N_EDGES/32)+7)/8*8), dim3(256), 0, stream,
                           perm_s, src_s, dst_s, ea,
                           ew1 + (size_t)i*4*HID, eb1 + (size_t)i*HID,
                           whi + (size_t)i*128*512, wlo + (size_t)i*128*512,
                           eb2 + (size_t)i*HID,
                           x, agg);
        hipLaunchKernelGGL(node_update_mfma_kernel, dim3((N_NODES+15)/16), dim3(256), 0, stream,
                           agg, nwhi + (size_t)i*128*512, nwlo + (size_t)i*128*512,
                           nb + (size_t)i*HID, x);
    }

    // ---- pool + readout ----
    hipMemsetAsync(sums, 0, ((size_t)N_GRAPHS*HID + N_GRAPHS)*sizeof(float), stream);
    hipLaunchKernelGGL(pool_kernel, dim3((N_NODES+31)/32), dim3(256), 0, stream, x, batch, sums, cnts);
    hipLaunchKernelGGL(readout_kernel, dim3(N_GRAPHS), dim3(256), 0, stream,
                       sums, cnts, rw1, rb1, rw2, rb2, rw3, rb3, out);
}

// Round 9
// 870.551 us; speedup vs baseline: 1.4503x; 1.1145x over previous
//
#include <hip/hip_runtime.h>
#include <math.h>

#define N_NODES  25000
#define N_EDGES  300000
#define N_GRAPHS 256
#define EMB_DIM  92
#define HID      256

typedef short bf16x8 __attribute__((ext_vector_type(8)));
typedef float f32x4  __attribute__((ext_vector_type(4)));

// fast softplus == jax.nn.softplus to ~1e-6 abs
__device__ __forceinline__ float softplusf(float x){
    return fmaxf(x, 0.0f) + __logf(1.0f + __expf(-fabsf(x)));
}
__device__ __forceinline__ unsigned short f2bf(float f){
    unsigned int u = __float_as_uint(f);
    unsigned int r = (u + 0x7FFFu + ((u >> 16) & 1u)) >> 16;   // RNE
    return (unsigned short)r;
}
__device__ __forceinline__ float bf2f(unsigned short b){
    return __uint_as_float(((unsigned int)b) << 16);
}
// truncation hi/lo split (A operand of node updates; 3-MFMA scheme)
__device__ __forceinline__ void split_bf(float h, unsigned short& hi, unsigned short& lo){
    const unsigned int u = __float_as_uint(h);
    hi = (unsigned short)(u >> 16);
    const float r = h - __uint_as_float(u & 0xFFFF0000u);
    lo = (unsigned short)(__float_as_uint(r) >> 16);
}
// XCD-contiguity swizzle (perf heuristic only)
__device__ __forceinline__ int xcd_window(int nwin){
    const int per = (nwin + 7) >> 3;
    const int win = (blockIdx.x & 7) * per + (blockIdx.x >> 3);
    return (win < nwin) ? win : -1;
}

// ---------------------------------------------------------------- embedding gather
__global__ void gather_emb_kernel(const int* __restrict__ atoms,
                                  const float* __restrict__ emb,
                                  float* __restrict__ x)
{
    const int n = blockIdx.x;
    const int c = threadIdx.x;
    if (c < EMB_DIM){
        const int a = atoms[n];
        x[(size_t)n*EMB_DIM + c] = emb[(size_t)a*EMB_DIM + c];
    }
}

// ---------------------------------------------------------------- counting sort by dst
__global__ __launch_bounds__(256) void hist_kernel(const int* __restrict__ dst, int* __restrict__ hist){
    const int e = blockIdx.x*256 + threadIdx.x;
    if (e < N_EDGES) atomicAdd(&hist[dst[e]], 1);
}

__global__ __launch_bounds__(1024) void scan_kernel(const int* __restrict__ hist, int* __restrict__ cursor){
    __shared__ int chunk[1024];
    const int t = threadIdx.x;
    const int base = t*25;                     // 1024*25 = 25600 >= 25000
    int local[25];
    int s = 0;
    #pragma unroll
    for (int i=0;i<25;i++){
        const int idx = base+i;
        const int v = (idx < N_NODES) ? hist[idx] : 0;
        local[i] = s; s += v;
    }
    chunk[t] = s;
    __syncthreads();
    for (int off=1; off<1024; off<<=1){
        int v = (t >= off) ? chunk[t-off] : 0;
        __syncthreads();
        chunk[t] += v;
        __syncthreads();
    }
    const int pre = (t > 0) ? chunk[t-1] : 0;
    #pragma unroll
    for (int i=0;i<25;i++){
        const int idx = base+i;
        if (idx < N_NODES) cursor[idx] = pre + local[i];
    }
}

__global__ __launch_bounds__(256) void scatter_kernel(const int* __restrict__ src, const int* __restrict__ dst,
                                                      int* __restrict__ cursor,
                                                      int* __restrict__ perm_s, int* __restrict__ src_s,
                                                      int* __restrict__ dst_s){
    const int e = blockIdx.x*256 + threadIdx.x;
    if (e < N_EDGES){
        const int d = dst[e];
        const int pos = atomicAdd(&cursor[d], 1);
        perm_s[pos] = e;
        src_s[pos]  = src[e];
        dst_s[pos]  = d;
    }
}

// ---------------------------------------------------------------- pack [3][256][256] weights into MFMA B-frag hi/lo bf16 (K=256, 8 k-tiles)
__global__ __launch_bounds__(256) void pack_w_kernel(const float* __restrict__ w,
                                                     unsigned short* __restrict__ whi,
                                                     unsigned short* __restrict__ wlo)
{
    const int f     = blockIdx.x;          // 0..383
    const int layer = f >> 7;
    const int rem   = f & 127;
    const int ntile = rem >> 3;
    const int k8    = rem & 7;
    for (int i = threadIdx.x; i < 512; i += 256){
        const int lane = i >> 3, j = i & 7;
        const int k = k8*32 + (lane >> 4)*8 + j;
        const int n = ntile*16 + (lane & 15);
        const float v = w[(size_t)layer*HID*HID + (size_t)k*HID + n];
        const unsigned short hb = f2bf(v);
        whi[(size_t)f*512 + i] = hb;
        wlo[(size_t)f*512 + i] = f2bf(v - bf2f(hb));
    }
}

// ---------------------------------------------------------------- generic padded packer: [Kin x Nin] -> frags (3 k-tiles of 32, zero-pad)
// frag f = ntile*3 + k8; grid = nNtiles*3
__global__ __launch_bounds__(256) void pack_w_pad_kernel(const float* __restrict__ w,
                                                         int Kin, int Nin, int ldn,
                                                         unsigned short* __restrict__ whi,
                                                         unsigned short* __restrict__ wlo)
{
    const int f  = blockIdx.x;
    const int k8 = f % 3;
    const int ntile = f / 3;
    for (int i = threadIdx.x; i < 512; i += 256){
        const int lane = i >> 3, j = i & 7;
        const int k = k8*32 + (lane >> 4)*8 + j;
        const int n = ntile*16 + (lane & 15);
        float v = 0.0f;
        if (k < Kin && n < Nin) v = w[(size_t)k*ldn + n];
        const unsigned short hb = f2bf(v);
        whi[(size_t)f*512 + i] = hb;
        wlo[(size_t)f*512 + i] = f2bf(v - bf2f(hb));
    }
}

// ---------------------------------------------------------------- layer-0 edge conv MFMA (C=92, K/N pad 96), 32 edges/block
// wave wv: m-tile = wv>>1 (16 edges), n-tiles = (wv&1)*3 + {0,1,2}
__global__ __launch_bounds__(256, 4) void edge_conv92_mfma_kernel(
    const int* __restrict__ perm_s, const int* __restrict__ src_s, const int* __restrict__ dst_s,
    const float* __restrict__ ea,
    const float* __restrict__ w1, const float* __restrict__ b1,     // [4][92],[92]
    const unsigned short* __restrict__ whi, const unsigned short* __restrict__ wlo,  // 18 frags
    const float* __restrict__ b2,                                    // [92]
    const float* __restrict__ x92, float* __restrict__ agg92)        // [N,92]
{
    constexpr int C = EMB_DIM;     // 92
    constexpr int KP = 96;
    constexpr int LDA = 104;       // ushorts; 104%8==0 so b128 reads stay 16B-aligned
    __shared__ unsigned short aHi[32][LDA];   // 6.5 KB
    __shared__ float eaS[32][4];
    __shared__ int   srcS[32];
    __shared__ int   dstS[32];

    const int win = xcd_window(N_EDGES/32);
    if (win < 0) return;
    const int e0  = win * 32;
    const int tid = threadIdx.x;

    if (tid < 128){
        const int e = tid >> 2, comp = tid & 3;
        eaS[e][comp] = ea[(size_t)perm_s[e0+e]*4 + comp];
    } else if (tid < 160){
        srcS[tid-128] = src_s[e0 + tid-128];
    } else if (tid < 192){
        dstS[tid-160] = dst_s[e0 + tid-160];
    }
    __syncthreads();

    // phase 1: h1 = softplus(ea@w1+b1), K zero-padded to 96
    for (int idx = tid; idx < 32*KP; idx += 256){
        const int e = idx / KP, k = idx - e*KP;
        float h = 0.0f;
        if (k < C){
            const float4 a = *(const float4*)&eaS[e][0];
            h = softplusf(fmaf(a.x, w1[k], fmaf(a.y, w1[C+k],
                          fmaf(a.z, w1[2*C+k], fmaf(a.w, w1[3*C+k], b1[k])))));
        }
        aHi[e][k] = f2bf(h);
    }
    __syncthreads();

    const int lane = tid & 63, wv = tid >> 6;
    const int quad = lane >> 4, fcol = lane & 15;
    const int m  = wv >> 1;          // 0/1
    const int nt0 = (wv & 1)*3;      // first of 3 n-tiles

    f32x4 acc[3];
    #pragma unroll
    for (int t=0;t<3;t++)
        #pragma unroll
        for (int j=0;j<4;j++) acc[t][j] = 0.0f;

    for (int k8=0;k8<3;k8++){
        const bf16x8 ah = *(const bf16x8*)(&aHi[m*16 + fcol][0] + k8*32 + quad*8);
        #pragma unroll
        for (int t=0;t<3;t++){
            const int fi = (nt0 + t)*3 + k8;
            const bf16x8 bh = *(const bf16x8*)(whi + (size_t)fi*512 + lane*8);
            const bf16x8 bl = *(const bf16x8*)(wlo + (size_t)fi*512 + lane*8);
            acc[t] = __builtin_amdgcn_mfma_f32_16x16x32_bf16(ah, bh, acc[t], 0, 0, 0);
            acc[t] = __builtin_amdgcn_mfma_f32_16x16x32_bf16(ah, bl, acc[t], 0, 0, 0);
        }
    }

    // epilogue: cols ncol = (nt0+t)*16 + fcol (guard < 92); edges m*16+quad*4..+3
    int   ncol[3]; float bb[3];
    #pragma unroll
    for (int t=0;t<3;t++){
        ncol[t] = (nt0 + t)*16 + fcol;
        bb[t] = (ncol[t] < C) ? b2[ncol[t]] : 0.0f;
    }

    const int ebase = m*16 + quad*4;
    float xv[4][3];
    #pragma unroll
    for (int i=0;i<4;i++){
        const int s = srcS[ebase + i];
        #pragma unroll
        for (int t=0;t<3;t++)
            xv[i][t] = (ncol[t] < C) ? x92[(size_t)s*C + ncol[t]] : 0.0f;
    }

    int dprev = dstS[ebase];
    float run[3] = {0.f,0.f,0.f};
    #pragma unroll
    for (int i=0;i<4;i++){
        const int d = dstS[ebase + i];
        if (d != dprev){
            #pragma unroll
            for (int t=0;t<3;t++)
                if (ncol[t] < C) atomicAdd(&agg92[(size_t)dprev*C + ncol[t]], run[t]);
            run[0]=run[1]=run[2]=0.0f;
            dprev = d;
        }
        #pragma unroll
        for (int t=0;t<3;t++)
            run[t] += (acc[t][i] + bb[t]) * xv[i][t];
    }
    #pragma unroll
    for (int t=0;t<3;t++)
        if (ncol[t] < C) atomicAdd(&agg92[(size_t)dprev*C + ncol[t]], run[t]);
}

// ---------------------------------------------------------------- node update 92->256 MFMA: x = softplus(agg92 @ nw_0 + nb_0)
__global__ __launch_bounds__(256) void node_update92_mfma_kernel(
    const float* __restrict__ agg92,
    const unsigned short* __restrict__ whi, const unsigned short* __restrict__ wlo,  // 48 frags
    const float* __restrict__ b, float* __restrict__ xout)
{
    constexpr int C = EMB_DIM;     // 92
    constexpr int KP = 96;
    constexpr int LDA = 104;
    __shared__ unsigned short aHi[16][LDA];
    __shared__ unsigned short aLo[16][LDA];

    const int n0  = blockIdx.x * 16;
    const int tid = threadIdx.x;

    for (int idx = tid; idx < 16*KP; idx += 256){
        const int i = idx / KP, k = idx - i*KP;
        const int node = n0 + i;
        float v = 0.0f;
        if (k < C && node < N_NODES) v = agg92[(size_t)node*C + k];
        unsigned short hb, lb;
        split_bf(v, hb, lb);
        aHi[i][k] = hb;
        aLo[i][k] = lb;
    }
    __syncthreads();

    const int lane = tid & 63, wv = tid >> 6;
    const int quad = lane >> 4, fcol = lane & 15;

    f32x4 acc[4];
    #pragma unroll
    for (int t=0;t<4;t++)
        #pragma unroll
        for (int j=0;j<4;j++) acc[t][j] = 0.0f;

    const unsigned short* aHrow = &aHi[fcol][0];
    const unsigned short* aLrow = &aLo[fcol][0];

    for (int k8=0;k8<3;k8++){
        const bf16x8 ah = *(const bf16x8*)(aHrow + k8*32 + quad*8);
        const bf16x8 al = *(const bf16x8*)(aLrow + k8*32 + quad*8);
        #pragma unroll
        for (int t=0;t<4;t++){
            const int fi = (wv*4 + t)*3 + k8;
            const bf16x8 bh = *(const bf16x8*)(whi + (size_t)fi*512 + lane*8);
            const bf16x8 bl = *(const bf16x8*)(wlo + (size_t)fi*512 + lane*8);
            acc[t] = __builtin_amdgcn_mfma_f32_16x16x32_bf16(ah, bh, acc[t], 0, 0, 0);
            acc[t] = __builtin_amdgcn_mfma_f32_16x16x32_bf16(ah, bl, acc[t], 0, 0, 0);
            acc[t] = __builtin_amdgcn_mfma_f32_16x16x32_bf16(al, bh, acc[t], 0, 0, 0);
        }
    }

    #pragma unroll
    for (int i=0;i<4;i++){
        const int node = n0 + quad*4 + i;
        if (node < N_NODES){
            #pragma unroll
            for (int t=0;t<4;t++){
                const int n = (wv*4 + t)*16 + fcol;
                xout[(size_t)node*HID + n] = softplusf(acc[t][i] + b[n]);
            }
        }
    }
}

// ---------------------------------------------------------------- layers 1-3 edge conv, MFMA, 32 edges/block
// A = bf16(h1); B = w2 hi/lo (2 MFMA). Window edge e = q*8 + m*4 + i lives in
// MFMA row m*16 + q*4 + i, so each quad owns one CONTIGUOUS 8-edge dst-sorted chain.
__global__ __launch_bounds__(256, 4) void edge_conv256_mfma_kernel(
    const int* __restrict__ perm_s, const int* __restrict__ src_s, const int* __restrict__ dst_s,
    const float* __restrict__ ea,
    const float* __restrict__ w1, const float* __restrict__ b1,
    const unsigned short* __restrict__ whi, const unsigned short* __restrict__ wlo,
    const float* __restrict__ b2,
    const float* __restrict__ x, float* __restrict__ agg)
{
    constexpr int C = HID;
    constexpr int LDA = C + 8;                 // ushort row stride 528 B -> 2-way bank alias (free)
    constexpr int EPB = 32;
    __shared__ unsigned short aHi[EPB][LDA];   // 16.9 KB
    __shared__ float eaS[EPB][4];
    __shared__ int   srcS[EPB];
    __shared__ int   dstS[EPB];

    const int win = xcd_window(N_EDGES/EPB);   // 9375 windows
    if (win < 0) return;
    const int e0  = win * EPB;
    const int tid = threadIdx.x;

    if (tid < 128){
        const int e = tid >> 2, comp = tid & 3;
        eaS[e][comp] = ea[(size_t)perm_s[e0+e]*4 + comp];
    } else if (tid < 160){
        srcS[tid-128] = src_s[e0 + tid-128];
    } else if (tid < 192){
        dstS[tid-160] = dst_s[e0 + tid-160];
    }
    __syncthreads();

    // phase 1: h1 = softplus(ea@w1+b1) -> bf16 LDS rows permuted per chain map
    {
        const int k = tid;
        const float w10 = w1[k], w11 = w1[C+k], w12 = w1[2*C+k], w13 = w1[3*C+k];
        const float bk  = b1[k];
        #pragma unroll
        for (int e=0;e<EPB;e++){
            const float4 a = *(const float4*)&eaS[e][0];   // LDS broadcast
            const float v = fmaf(a.x,w10,fmaf(a.y,w11,fmaf(a.z,w12,fmaf(a.w,w13,bk))));
            const int q = e >> 3, m = (e >> 2) & 1, i = e & 3;
            aHi[m*16 + q*4 + i][k] = f2bf(softplusf(v));
        }
    }
    __syncthreads();

    const int lane = tid & 63, wv = tid >> 6;
    const int quad = lane >> 4, fcol = lane & 15;

    f32x4 acc[2][4];
    #pragma unroll
    for (int m=0;m<2;m++)
        #pragma unroll
        for (int t=0;t<4;t++)
            #pragma unroll
            for (int j=0;j<4;j++) acc[m][t][j] = 0.0f;

    for (int k8=0;k8<8;k8++){
        bf16x8 ah[2];
        #pragma unroll
        for (int m=0;m<2;m++)
            ah[m] = *(const bf16x8*)(&aHi[m*16 + fcol][0] + k8*32 + quad*8);
        #pragma unroll
        for (int t=0;t<4;t++){
            const int fi = (wv*4 + t)*8 + k8;
            const bf16x8 bh = *(const bf16x8*)(whi + (size_t)fi*512 + lane*8);
            const bf16x8 bl = *(const bf16x8*)(wlo + (size_t)fi*512 + lane*8);
            #pragma unroll
            for (int m=0;m<2;m++){
                acc[m][t] = __builtin_amdgcn_mfma_f32_16x16x32_bf16(ah[m], bh, acc[m][t], 0, 0, 0);
                acc[m][t] = __builtin_amdgcn_mfma_f32_16x16x32_bf16(ah[m], bl, acc[m][t], 0, 0, 0);
            }
        }
    }

    // epilogue: quad q owns edges q*8..q*8+7 (value for j: acc[j>>2][t][j&3])
    float bb[4];
    #pragma unroll
    for (int t=0;t<4;t++) bb[t] = b2[(wv*4 + t)*16 + fcol];

    const int ebase = quad*8;
    float xv[8][4];
    #pragma unroll
    for (int j=0;j<8;j++){
        const int s = srcS[ebase + j];
        #pragma unroll
        for (int t=0;t<4;t++)
            xv[j][t] = x[(size_t)s*C + (wv*4 + t)*16 + fcol];
    }

    int dprev = dstS[ebase];
    float run[4] = {0.f,0.f,0.f,0.f};
    #pragma unroll
    for (int j=0;j<8;j++){
        const int d = dstS[ebase + j];
        if (d != dprev){
            #pragma unroll
            for (int t=0;t<4;t++){
                atomicAdd(&agg[(size_t)dprev*C + (wv*4 + t)*16 + fcol], run[t]);
                run[t] = 0.0f;
            }
            dprev = d;
        }
        const int m = j >> 2, i = j & 3;
        #pragma unroll
        for (int t=0;t<4;t++)
            run[t] += (acc[m][t][i] + bb[t]) * xv[j][t];
    }
    #pragma unroll
    for (int t=0;t<4;t++)
        atomicAdd(&agg[(size_t)dprev*C + (wv*4 + t)*16 + fcol], run[t]);
}

// ---------------------------------------------------------------- node update MFMA (CIN=256): x = softplus(agg @ nw + nb)
__global__ __launch_bounds__(256) void node_update_mfma_kernel(
    const float* __restrict__ agg,
    const unsigned short* __restrict__ whi, const unsigned short* __restrict__ wlo,
    const float* __restrict__ b, float* __restrict__ xout)
{
    constexpr int C = HID;
    constexpr int LDA = C + 8;
    __shared__ unsigned short aHi[16][LDA];
    __shared__ unsigned short aLo[16][LDA];

    const int n0  = blockIdx.x * 16;
    const int tid = threadIdx.x;

    #pragma unroll
    for (int it=0; it<16; it++){
        const int node = n0 + it;
        const float v = (node < N_NODES) ? agg[(size_t)node*C + tid] : 0.0f;
        unsigned short hb, lb;
        split_bf(v, hb, lb);
        aHi[it][tid] = hb;
        aLo[it][tid] = lb;
    }
    __syncthreads();

    const int lane = tid & 63, wv = tid >> 6;
    const int quad = lane >> 4, fcol = lane & 15;

    f32x4 acc[4];
    #pragma unroll
    for (int t=0;t<4;t++)
        #pragma unroll
        for (int j=0;j<4;j++) acc[t][j] = 0.0f;

    const unsigned short* aHrow = &aHi[fcol][0];
    const unsigned short* aLrow = &aLo[fcol][0];

    for (int k8=0;k8<8;k8++){
        const bf16x8 ah = *(const bf16x8*)(aHrow + k8*32 + quad*8);
        const bf16x8 al = *(const bf16x8*)(aLrow + k8*32 + quad*8);
        #pragma unroll
        for (int t=0;t<4;t++){
            const int fi = (wv*4 + t)*8 + k8;
            const bf16x8 bh = *(const bf16x8*)(whi + (size_t)fi*512 + lane*8);
            const bf16x8 bl = *(const bf16x8*)(wlo + (size_t)fi*512 + lane*8);
            acc[t] = __builtin_amdgcn_mfma_f32_16x16x32_bf16(ah, bh, acc[t], 0, 0, 0);
            acc[t] = __builtin_amdgcn_mfma_f32_16x16x32_bf16(ah, bl, acc[t], 0, 0, 0);
            acc[t] = __builtin_amdgcn_mfma_f32_16x16x32_bf16(al, bh, acc[t], 0, 0, 0);
        }
    }

    #pragma unroll
    for (int i=0;i<4;i++){
        const int node = n0 + quad*4 + i;
        if (node < N_NODES){
            #pragma unroll
            for (int t=0;t<4;t++){
                const int n = (wv*4 + t)*16 + fcol;
                xout[(size_t)node*C + n] = softplusf(acc[t][i] + b[n]);
            }
        }
    }
}

// ---------------------------------------------------------------- mean pool, run-merged (batch is sorted)
__global__ __launch_bounds__(256) void pool_kernel(
    const float* __restrict__ x, const int* __restrict__ batch,
    float* __restrict__ sums, float* __restrict__ cnts)
{
    constexpr int NPB = 32;
    const int n0 = blockIdx.x * NPB;
    const int c  = threadIdx.x;
    int gprev = batch[n0];
    float run = 0.0f, crun = 0.0f;
    for (int i=0;i<NPB;i++){
        const int n = n0 + i;
        if (n >= N_NODES) break;
        const int g = batch[n];
        if (g != gprev){
            atomicAdd(&sums[(size_t)gprev*HID + c], run);
            if (c == 0) atomicAdd(&cnts[gprev], crun);
            run = 0.0f; crun = 0.0f; gprev = g;
        }
        run  += x[(size_t)n*HID + c];
        crun += 1.0f;
    }
    atomicAdd(&sums[(size_t)gprev*HID + c], run);
    if (c == 0) atomicAdd(&cnts[gprev], crun);
}

// ---------------------------------------------------------------- readout MLP (one block per graph)
__global__ __launch_bounds__(256) void readout_kernel(
    const float* __restrict__ sums, const float* __restrict__ cnts,
    const float* __restrict__ rw1, const float* __restrict__ rb1,
    const float* __restrict__ rw2, const float* __restrict__ rb2,
    const float* __restrict__ rw3, const float* __restrict__ rb3,
    float* __restrict__ out)
{
    __shared__ float g[HID];
    __shared__ float h[HID];
    __shared__ float h2[HID/2];
    __shared__ float red[256];
    const int gi = blockIdx.x;
    const int t  = threadIdx.x;
    const float cnt = fmaxf(cnts[gi], 1.0f);
    g[t] = sums[(size_t)gi*HID + t] / cnt;
    __syncthreads();
    float acc = rb1[t];
    for (int k=0;k<HID;k++) acc = fmaf(g[k], rw1[(size_t)k*HID + t], acc);
    h[t] = softplusf(acc);
    __syncthreads();
    if (t < HID/2){
        float a2 = rb2[t];
        for (int k=0;k<HID;k++) a2 = fmaf(h[k], rw2[(size_t)k*(HID/2) + t], a2);
        h2[t] = softplusf(a2);
    }
    __syncthreads();
    red[t] = (t < HID/2) ? h2[t]*rw3[t] : 0.0f;
    __syncthreads();
    for (int s2=128; s2>0; s2>>=1){
        if (t < s2) red[t] += red[t+s2];
        __syncthreads();
    }
    if (t == 0) out[gi] = red[0] + rb3[0];
}

// ---------------------------------------------------------------- launcher
extern "C" void kernel_launch(void* const* d_in, const int* in_sizes, int n_in,
                              void* d_out, int out_size, void* d_ws, size_t ws_size,
                              hipStream_t stream)
{
    const int*   x_atoms = (const int*)d_in[0];
    const int*   eidx    = (const int*)d_in[1];
    const int*   src     = eidx;               // edge_index[0]
    const int*   dst     = eidx + N_EDGES;     // edge_index[1]
    const float* ea      = (const float*)d_in[2];
    const int*   batch   = (const int*)d_in[3];
    const float* emb     = (const float*)d_in[4];
    const float* ew1_0   = (const float*)d_in[5];
    const float* eb1_0   = (const float*)d_in[6];
    const float* ew2_0   = (const float*)d_in[7];
    const float* eb2_0   = (const float*)d_in[8];
    const float* nw_0    = (const float*)d_in[9];
    const float* nb_0    = (const float*)d_in[10];
    const float* ew1     = (const float*)d_in[11];
    const float* eb1     = (const float*)d_in[12];
    const float* ew2     = (const float*)d_in[13];
    const float* eb2     = (const float*)d_in[14];
    const float* nw      = (const float*)d_in[15];
    const float* nb      = (const float*)d_in[16];
    const float* rw1     = (const float*)d_in[17];
    const float* rb1     = (const float*)d_in[18];
    const float* rw2     = (const float*)d_in[19];
    const float* rb2     = (const float*)d_in[20];
    const float* rw3     = (const float*)d_in[21];
    const float* rb3     = (const float*)d_in[22];
    float* out = (float*)d_out;

    float* x    = (float*)d_ws;
    float* agg  = x   + (size_t)N_NODES*HID;
    float* sums = agg + (size_t)N_NODES*HID;
    float* cnts = sums + (size_t)N_GRAPHS*HID;
    unsigned short* whi  = (unsigned short*)(cnts + N_GRAPHS);
    unsigned short* wlo  = whi  + (size_t)3*128*512;
    unsigned short* nwhi = wlo  + (size_t)3*128*512;
    unsigned short* nwlo = nwhi + (size_t)3*128*512;
    unsigned short* w92hi  = nwlo  + (size_t)3*128*512;   // 18 frags
    unsigned short* w92lo  = w92hi + (size_t)18*512;
    unsigned short* nw92hi = w92lo + (size_t)18*512;      // 48 frags
    unsigned short* nw92lo = nw92hi + (size_t)48*512;
    int* hist   = (int*)(nw92lo + (size_t)48*512);
    int* cursor = hist   + N_NODES;
    int* perm_s = cursor + N_NODES;
    int* src_s  = perm_s + N_EDGES;
    int* dst_s  = src_s  + N_EDGES;

    // ---- counting sort of edges by dst (once per launch) ----
    hipMemsetAsync(hist, 0, N_NODES*sizeof(int), stream);
    hipLaunchKernelGGL(hist_kernel, dim3((N_EDGES+255)/256), dim3(256), 0, stream, dst, hist);
    hipLaunchKernelGGL(scan_kernel, dim3(1), dim3(1024), 0, stream, hist, cursor);
    hipLaunchKernelGGL(scatter_kernel, dim3((N_EDGES+255)/256), dim3(256), 0, stream,
                       src, dst, cursor, perm_s, src_s, dst_s);

    // ---- pack weights for MFMA ----
    hipLaunchKernelGGL(pack_w_kernel, dim3(384), dim3(256), 0, stream, ew2, whi, wlo);
    hipLaunchKernelGGL(pack_w_kernel, dim3(384), dim3(256), 0, stream, nw, nwhi, nwlo);
    hipLaunchKernelGGL(pack_w_pad_kernel, dim3(18), dim3(256), 0, stream, ew2_0, EMB_DIM, EMB_DIM, EMB_DIM, w92hi, w92lo);
    hipLaunchKernelGGL(pack_w_pad_kernel, dim3(48), dim3(256), 0, stream, nw_0, EMB_DIM, HID, HID, nw92hi, nw92lo);

    // ---- layer 0 (C = 92), MFMA ----
    hipLaunchKernelGGL(gather_emb_kernel, dim3(N_NODES), dim3(128), 0, stream, x_atoms, emb, x);
    hipMemsetAsync(agg, 0, (size_t)N_NODES*EMB_DIM*sizeof(float), stream);
    hipLaunchKernelGGL(edge_conv92_mfma_kernel, dim3(((N_EDGES/32)+7)/8*8), dim3(256), 0, stream,
                       perm_s, src_s, dst_s, ea, ew1_0, eb1_0, w92hi, w92lo, eb2_0, x, agg);
    // x (N,92 region) consumed; write N,256 output into x buffer (stride HID) — safe since
    // node_update reads agg only.  x layout switches from [N,92] to [N,256] here.
    hipLaunchKernelGGL(node_update92_mfma_kernel, dim3((N_NODES+15)/16), dim3(256), 0, stream,
                       agg, nw92hi, nw92lo, nb_0, x);

    // ---- layers 1..3 (C = 256), MFMA ----
    for (int i=0;i<3;i++){
        hipMemsetAsync(agg, 0, (size_t)N_NODES*HID*sizeof(float), stream);
        hipLaunchKernelGGL(edge_conv256_mfma_kernel, dim3(((N_EDGES/32)+7)/8*8), dim3(256), 0, stream,
                           perm_s, src_s, dst_s, ea,
                           ew1 + (size_t)i*4*HID, eb1 + (size_t)i*HID,
                           whi + (size_t)i*128*512, wlo + (size_t)i*128*512,
                           eb2 + (size_t)i*HID,
                           x, agg);
        hipLaunchKernelGGL(node_update_mfma_kernel, dim3((N_NODES+15)/16), dim3(256), 0, stream,
                           agg, nwhi + (size_t)i*128*512, nwlo + (size_t)i*128*512,
                           nb + (size_t)i*HID, x);
    }

    // ---- pool + readout ----
    hipMemsetAsync(sums, 0, ((size_t)N_GRAPHS*HID + N_GRAPHS)*sizeof(float), stream);
    hipLaunchKernelGGL(pool_kernel, dim3((N_NODES+31)/32), dim3(256), 0, stream, x, batch, sums, cnts);
    hipLaunchKernelGGL(readout_kernel, dim3(N_GRAPHS), dim3(256), 0, stream,
                       sums, cnts, rw1, rb1, rw2, rb2, rw3, rb3, out);
}

// Round 10
// 790.871 us; speedup vs baseline: 1.5965x; 1.1007x over previous
//
#include <hip/hip_runtime.h>
#include <math.h>

#define N_NODES  25000
#define N_EDGES  300000
#define N_GRAPHS 256
#define EMB_DIM  92
#define HID      256

typedef short bf16x8 __attribute__((ext_vector_type(8)));
typedef float f32x4  __attribute__((ext_vector_type(4)));

// fast softplus == jax.nn.softplus to ~1e-6 abs
__device__ __forceinline__ float softplusf(float x){
    return fmaxf(x, 0.0f) + __logf(1.0f + __expf(-fabsf(x)));
}
__device__ __forceinline__ unsigned short f2bf(float f){
    unsigned int u = __float_as_uint(f);
    unsigned int r = (u + 0x7FFFu + ((u >> 16) & 1u)) >> 16;   // RNE
    return (unsigned short)r;
}
__device__ __forceinline__ float bf2f(unsigned short b){
    return __uint_as_float(((unsigned int)b) << 16);
}
// truncation hi/lo split (A operand of node updates; 3-MFMA scheme)
__device__ __forceinline__ void split_bf(float h, unsigned short& hi, unsigned short& lo){
    const unsigned int u = __float_as_uint(h);
    hi = (unsigned short)(u >> 16);
    const float r = h - __uint_as_float(u & 0xFFFF0000u);
    lo = (unsigned short)(__float_as_uint(r) >> 16);
}
// XCD-contiguity swizzle (perf heuristic only)
__device__ __forceinline__ int xcd_window(int nwin){
    const int per = (nwin + 7) >> 3;
    const int win = (blockIdx.x & 7) * per + (blockIdx.x >> 3);
    return (win < nwin) ? win : -1;
}

// ---------------------------------------------------------------- embedding gather
__global__ void gather_emb_kernel(const int* __restrict__ atoms,
                                  const float* __restrict__ emb,
                                  float* __restrict__ x)
{
    const int n = blockIdx.x;
    const int c = threadIdx.x;
    if (c < EMB_DIM){
        const int a = atoms[n];
        x[(size_t)n*EMB_DIM + c] = emb[(size_t)a*EMB_DIM + c];
    }
}

// ---------------------------------------------------------------- counting sort by dst
__global__ __launch_bounds__(256) void hist_kernel(const int* __restrict__ dst, int* __restrict__ hist){
    const int e = blockIdx.x*256 + threadIdx.x;
    if (e < N_EDGES) atomicAdd(&hist[dst[e]], 1);
}

__global__ __launch_bounds__(1024) void scan_kernel(const int* __restrict__ hist, int* __restrict__ cursor){
    __shared__ int chunk[1024];
    const int t = threadIdx.x;
    const int base = t*25;                     // 1024*25 = 25600 >= 25000
    int local[25];
    int s = 0;
    #pragma unroll
    for (int i=0;i<25;i++){
        const int idx = base+i;
        const int v = (idx < N_NODES) ? hist[idx] : 0;
        local[i] = s; s += v;
    }
    chunk[t] = s;
    __syncthreads();
    for (int off=1; off<1024; off<<=1){
        int v = (t >= off) ? chunk[t-off] : 0;
        __syncthreads();
        chunk[t] += v;
        __syncthreads();
    }
    const int pre = (t > 0) ? chunk[t-1] : 0;
    #pragma unroll
    for (int i=0;i<25;i++){
        const int idx = base+i;
        if (idx < N_NODES) cursor[idx] = pre + local[i];
    }
}

__global__ __launch_bounds__(256) void scatter_kernel(const int* __restrict__ src, const int* __restrict__ dst,
                                                      int* __restrict__ cursor,
                                                      int* __restrict__ perm_s, int* __restrict__ src_s,
                                                      int* __restrict__ dst_s){
    const int e = blockIdx.x*256 + threadIdx.x;
    if (e < N_EDGES){
        const int d = dst[e];
        const int pos = atomicAdd(&cursor[d], 1);
        perm_s[pos] = e;
        src_s[pos]  = src[e];
        dst_s[pos]  = d;
    }
}

// ---------------------------------------------------------------- pack [3][256][256] weights into MFMA B-frag hi/lo bf16 (K=256, 8 k-tiles)
__global__ __launch_bounds__(256) void pack_w_kernel(const float* __restrict__ w,
                                                     unsigned short* __restrict__ whi,
                                                     unsigned short* __restrict__ wlo)
{
    const int f     = blockIdx.x;          // 0..383
    const int layer = f >> 7;
    const int rem   = f & 127;
    const int ntile = rem >> 3;
    const int k8    = rem & 7;
    for (int i = threadIdx.x; i < 512; i += 256){
        const int lane = i >> 3, j = i & 7;
        const int k = k8*32 + (lane >> 4)*8 + j;
        const int n = ntile*16 + (lane & 15);
        const float v = w[(size_t)layer*HID*HID + (size_t)k*HID + n];
        const unsigned short hb = f2bf(v);
        whi[(size_t)f*512 + i] = hb;
        wlo[(size_t)f*512 + i] = f2bf(v - bf2f(hb));
    }
}

// ---------------------------------------------------------------- generic padded packer: [Kin x Nin] -> frags (3 k-tiles of 32, zero-pad)
__global__ __launch_bounds__(256) void pack_w_pad_kernel(const float* __restrict__ w,
                                                         int Kin, int Nin, int ldn,
                                                         unsigned short* __restrict__ whi,
                                                         unsigned short* __restrict__ wlo)
{
    const int f  = blockIdx.x;
    const int k8 = f % 3;
    const int ntile = f / 3;
    for (int i = threadIdx.x; i < 512; i += 256){
        const int lane = i >> 3, j = i & 7;
        const int k = k8*32 + (lane >> 4)*8 + j;
        const int n = ntile*16 + (lane & 15);
        float v = 0.0f;
        if (k < Kin && n < Nin) v = w[(size_t)k*ldn + n];
        const unsigned short hb = f2bf(v);
        whi[(size_t)f*512 + i] = hb;
        wlo[(size_t)f*512 + i] = f2bf(v - bf2f(hb));
    }
}

// ---------------------------------------------------------------- layer-0 edge conv MFMA (C=92, K/N pad 96), 32 edges/block
__global__ __launch_bounds__(256, 4) void edge_conv92_mfma_kernel(
    const int* __restrict__ perm_s, const int* __restrict__ src_s, const int* __restrict__ dst_s,
    const float* __restrict__ ea,
    const float* __restrict__ w1, const float* __restrict__ b1,
    const unsigned short* __restrict__ whi, const unsigned short* __restrict__ wlo,  // 18 frags
    const float* __restrict__ b2,
    const float* __restrict__ x92, float* __restrict__ agg92)
{
    constexpr int C = EMB_DIM;     // 92
    constexpr int KP = 96;
    constexpr int LDA = 104;
    __shared__ unsigned short aHi[32][LDA];
    __shared__ float eaS[32][4];
    __shared__ int   srcS[32];
    __shared__ int   dstS[32];

    const int win = xcd_window(N_EDGES/32);
    if (win < 0) return;
    const int e0  = win * 32;
    const int tid = threadIdx.x;

    if (tid < 128){
        const int e = tid >> 2, comp = tid & 3;
        eaS[e][comp] = ea[(size_t)perm_s[e0+e]*4 + comp];
    } else if (tid < 160){
        srcS[tid-128] = src_s[e0 + tid-128];
    } else if (tid < 192){
        dstS[tid-160] = dst_s[e0 + tid-160];
    }
    __syncthreads();

    for (int idx = tid; idx < 32*KP; idx += 256){
        const int e = idx / KP, k = idx - e*KP;
        float h = 0.0f;
        if (k < C){
            const float4 a = *(const float4*)&eaS[e][0];
            h = softplusf(fmaf(a.x, w1[k], fmaf(a.y, w1[C+k],
                          fmaf(a.z, w1[2*C+k], fmaf(a.w, w1[3*C+k], b1[k])))));
        }
        aHi[e][k] = f2bf(h);
    }
    __syncthreads();

    const int lane = tid & 63, wv = tid >> 6;
    const int quad = lane >> 4, fcol = lane & 15;
    const int m  = wv >> 1;
    const int nt0 = (wv & 1)*3;

    f32x4 acc[3];
    #pragma unroll
    for (int t=0;t<3;t++)
        #pragma unroll
        for (int j=0;j<4;j++) acc[t][j] = 0.0f;

    for (int k8=0;k8<3;k8++){
        const bf16x8 ah = *(const bf16x8*)(&aHi[m*16 + fcol][0] + k8*32 + quad*8);
        #pragma unroll
        for (int t=0;t<3;t++){
            const int fi = (nt0 + t)*3 + k8;
            const bf16x8 bh = *(const bf16x8*)(whi + (size_t)fi*512 + lane*8);
            const bf16x8 bl = *(const bf16x8*)(wlo + (size_t)fi*512 + lane*8);
            acc[t] = __builtin_amdgcn_mfma_f32_16x16x32_bf16(ah, bh, acc[t], 0, 0, 0);
            acc[t] = __builtin_amdgcn_mfma_f32_16x16x32_bf16(ah, bl, acc[t], 0, 0, 0);
        }
    }

    int   ncol[3]; float bb[3];
    #pragma unroll
    for (int t=0;t<3;t++){
        ncol[t] = (nt0 + t)*16 + fcol;
        bb[t] = (ncol[t] < C) ? b2[ncol[t]] : 0.0f;
    }

    const int ebase = m*16 + quad*4;
    float xv[4][3];
    #pragma unroll
    for (int i=0;i<4;i++){
        const int s = srcS[ebase + i];
        #pragma unroll
        for (int t=0;t<3;t++)
            xv[i][t] = (ncol[t] < C) ? x92[(size_t)s*C + ncol[t]] : 0.0f;
    }

    int dprev = dstS[ebase];
    float run[3] = {0.f,0.f,0.f};
    #pragma unroll
    for (int i=0;i<4;i++){
        const int d = dstS[ebase + i];
        if (d != dprev){
            #pragma unroll
            for (int t=0;t<3;t++)
                if (ncol[t] < C) atomicAdd(&agg92[(size_t)dprev*C + ncol[t]], run[t]);
            run[0]=run[1]=run[2]=0.0f;
            dprev = d;
        }
        #pragma unroll
        for (int t=0;t<3;t++)
            run[t] += (acc[t][i] + bb[t]) * xv[i][t];
    }
    #pragma unroll
    for (int t=0;t<3;t++)
        if (ncol[t] < C) atomicAdd(&agg92[(size_t)dprev*C + ncol[t]], run[t]);
}

// ---------------------------------------------------------------- node update 92->256 MFMA
__global__ __launch_bounds__(256) void node_update92_mfma_kernel(
    const float* __restrict__ agg92,
    const unsigned short* __restrict__ whi, const unsigned short* __restrict__ wlo,  // 48 frags
    const float* __restrict__ b, float* __restrict__ xout)
{
    constexpr int C = EMB_DIM;
    constexpr int KP = 96;
    constexpr int LDA = 104;
    __shared__ unsigned short aHi[16][LDA];
    __shared__ unsigned short aLo[16][LDA];

    const int n0  = blockIdx.x * 16;
    const int tid = threadIdx.x;

    for (int idx = tid; idx < 16*KP; idx += 256){
        const int i = idx / KP, k = idx - i*KP;
        const int node = n0 + i;
        float v = 0.0f;
        if (k < C && node < N_NODES) v = agg92[(size_t)node*C + k];
        unsigned short hb, lb;
        split_bf(v, hb, lb);
        aHi[i][k] = hb;
        aLo[i][k] = lb;
    }
    __syncthreads();

    const int lane = tid & 63, wv = tid >> 6;
    const int quad = lane >> 4, fcol = lane & 15;

    f32x4 acc[4];
    #pragma unroll
    for (int t=0;t<4;t++)
        #pragma unroll
        for (int j=0;j<4;j++) acc[t][j] = 0.0f;

    const unsigned short* aHrow = &aHi[fcol][0];
    const unsigned short* aLrow = &aLo[fcol][0];

    for (int k8=0;k8<3;k8++){
        const bf16x8 ah = *(const bf16x8*)(aHrow + k8*32 + quad*8);
        const bf16x8 al = *(const bf16x8*)(aLrow + k8*32 + quad*8);
        #pragma unroll
        for (int t=0;t<4;t++){
            const int fi = (wv*4 + t)*3 + k8;
            const bf16x8 bh = *(const bf16x8*)(whi + (size_t)fi*512 + lane*8);
            const bf16x8 bl = *(const bf16x8*)(wlo + (size_t)fi*512 + lane*8);
            acc[t] = __builtin_amdgcn_mfma_f32_16x16x32_bf16(ah, bh, acc[t], 0, 0, 0);
            acc[t] = __builtin_amdgcn_mfma_f32_16x16x32_bf16(ah, bl, acc[t], 0, 0, 0);
            acc[t] = __builtin_amdgcn_mfma_f32_16x16x32_bf16(al, bh, acc[t], 0, 0, 0);
        }
    }

    #pragma unroll
    for (int i=0;i<4;i++){
        const int node = n0 + quad*4 + i;
        if (node < N_NODES){
            #pragma unroll
            for (int t=0;t<4;t++){
                const int n = (wv*4 + t)*16 + fcol;
                xout[(size_t)node*HID + n] = softplusf(acc[t][i] + b[n]);
            }
        }
    }
}

// ---------------------------------------------------------------- layers 1-3 edge conv, MFMA, 64 edges/block
// Quad q owns a CONTIGUOUS 16-edge dst-sorted chain (edges q*16..q*16+15),
// giving ~2.25 flushes/chain (vs 1.85 per 8-edge) -> ~0.61x atomics.
// Window edge e (q=e>>4, j=e&15) lives in MFMA m-tile m=j>>2, row q*4+(j&3).
__global__ __launch_bounds__(256, 4) void edge_conv256_mfma_kernel(
    const int* __restrict__ perm_s, const int* __restrict__ src_s, const int* __restrict__ dst_s,
    const float* __restrict__ ea,
    const float* __restrict__ w1, const float* __restrict__ b1,
    const unsigned short* __restrict__ whi, const unsigned short* __restrict__ wlo,
    const float* __restrict__ b2,
    const float* __restrict__ x, float* __restrict__ agg)
{
    constexpr int C = HID;
    constexpr int LDA = C + 8;                 // 528 B row stride
    constexpr int EPB = 64;
    constexpr int NWIN = (N_EDGES + EPB - 1) / EPB;   // 4688
    __shared__ unsigned short aHi[EPB][LDA];   // 33.8 KB
    __shared__ float eaS[EPB][4];
    __shared__ int   srcS[EPB];
    __shared__ int   dstS[EPB];

    const int win = xcd_window(NWIN);
    if (win < 0) return;
    const int e0  = win * EPB;
    const int tid = threadIdx.x;

    // stage ea[perm], src, dst cooperatively (tail edges clamped; zeroed later)
    {
        const int e = tid >> 2, comp = tid & 3;
        const int eid = min(e0 + e, N_EDGES-1);
        eaS[e][comp] = ea[(size_t)perm_s[eid]*4 + comp];
        if (tid < EPB){
            const int eid2 = min(e0 + tid, N_EDGES-1);
            srcS[tid] = src_s[eid2];
            dstS[tid] = dst_s[eid2];   // padded edges inherit last valid dst (contribution is 0)
        }
    }
    __syncthreads();

    // phase 1: h1 = softplus(ea@w1+b1) -> bf16 LDS rows permuted per chain map
    {
        const int k = tid;
        const float w10 = w1[k], w11 = w1[C+k], w12 = w1[2*C+k], w13 = w1[3*C+k];
        const float bk  = b1[k];
        #pragma unroll
        for (int e=0;e<EPB;e++){
            const float4 a = *(const float4*)&eaS[e][0];
            const float v = fmaf(a.x,w10,fmaf(a.y,w11,fmaf(a.z,w12,fmaf(a.w,w13,bk))));
            const int q = e >> 4, j = e & 15;
            aHi[(j>>2)*16 + q*4 + (j&3)][k] = f2bf(softplusf(v));
        }
    }
    __syncthreads();

    const int lane = tid & 63, wv = tid >> 6;
    const int quad = lane >> 4, fcol = lane & 15;

    f32x4 acc[4][4];     // [m-tile][n-tile]
    #pragma unroll
    for (int m=0;m<4;m++)
        #pragma unroll
        for (int t=0;t<4;t++)
            #pragma unroll
            for (int j=0;j<4;j++) acc[m][t][j] = 0.0f;

    for (int k8=0;k8<8;k8++){
        bf16x8 ah[4];
        #pragma unroll
        for (int m=0;m<4;m++)
            ah[m] = *(const bf16x8*)(&aHi[m*16 + fcol][0] + k8*32 + quad*8);
        #pragma unroll
        for (int t=0;t<4;t++){
            const int fi = (wv*4 + t)*8 + k8;
            const bf16x8 bh = *(const bf16x8*)(whi + (size_t)fi*512 + lane*8);
            const bf16x8 bl = *(const bf16x8*)(wlo + (size_t)fi*512 + lane*8);
            #pragma unroll
            for (int m=0;m<4;m++){
                acc[m][t] = __builtin_amdgcn_mfma_f32_16x16x32_bf16(ah[m], bh, acc[m][t], 0, 0, 0);
                acc[m][t] = __builtin_amdgcn_mfma_f32_16x16x32_bf16(ah[m], bl, acc[m][t], 0, 0, 0);
            }
        }
    }

    // epilogue: quad owns window edges quad*16..quad*16+15; value of edge j: acc[j>>2][t][j&3]
    float bb[4];
    #pragma unroll
    for (int t=0;t<4;t++) bb[t] = b2[(wv*4 + t)*16 + fcol];

    const int ebase = quad*16;
    int dprev = dstS[ebase];
    float run[4] = {0.f,0.f,0.f,0.f};
    #pragma unroll
    for (int jj=0; jj<16; jj+=4){
        // hoist 4 edges' x-gathers (16 loads) to keep them in flight
        float xv[4][4];
        #pragma unroll
        for (int j2=0;j2<4;j2++){
            const int j = jj + j2;
            const int s = srcS[ebase + j];
            const bool valid = (e0 + ebase + j) < N_EDGES;
            #pragma unroll
            for (int t=0;t<4;t++)
                xv[j2][t] = valid ? x[(size_t)s*C + (wv*4 + t)*16 + fcol] : 0.0f;
        }
        #pragma unroll
        for (int j2=0;j2<4;j2++){
            const int j = jj + j2;
            const int d = dstS[ebase + j];
            if (d != dprev){
                #pragma unroll
                for (int t=0;t<4;t++){
                    atomicAdd(&agg[(size_t)dprev*C + (wv*4 + t)*16 + fcol], run[t]);
                    run[t] = 0.0f;
                }
                dprev = d;
            }
            const int m = j >> 2, i = j & 3;
            #pragma unroll
            for (int t=0;t<4;t++)
                run[t] += (acc[m][t][i] + bb[t]) * xv[j2][t];
        }
    }
    #pragma unroll
    for (int t=0;t<4;t++)
        atomicAdd(&agg[(size_t)dprev*C + (wv*4 + t)*16 + fcol], run[t]);
}

// ---------------------------------------------------------------- node update MFMA (CIN=256)
__global__ __launch_bounds__(256) void node_update_mfma_kernel(
    const float* __restrict__ agg,
    const unsigned short* __restrict__ whi, const unsigned short* __restrict__ wlo,
    const float* __restrict__ b, float* __restrict__ xout)
{
    constexpr int C = HID;
    constexpr int LDA = C + 8;
    __shared__ unsigned short aHi[16][LDA];
    __shared__ unsigned short aLo[16][LDA];

    const int n0  = blockIdx.x * 16;
    const int tid = threadIdx.x;

    #pragma unroll
    for (int it=0; it<16; it++){
        const int node = n0 + it;
        const float v = (node < N_NODES) ? agg[(size_t)node*C + tid] : 0.0f;
        unsigned short hb, lb;
        split_bf(v, hb, lb);
        aHi[it][tid] = hb;
        aLo[it][tid] = lb;
    }
    __syncthreads();

    const int lane = tid & 63, wv = tid >> 6;
    const int quad = lane >> 4, fcol = lane & 15;

    f32x4 acc[4];
    #pragma unroll
    for (int t=0;t<4;t++)
        #pragma unroll
        for (int j=0;j<4;j++) acc[t][j] = 0.0f;

    const unsigned short* aHrow = &aHi[fcol][0];
    const unsigned short* aLrow = &aLo[fcol][0];

    for (int k8=0;k8<8;k8++){
        const bf16x8 ah = *(const bf16x8*)(aHrow + k8*32 + quad*8);
        const bf16x8 al = *(const bf16x8*)(aLrow + k8*32 + quad*8);
        #pragma unroll
        for (int t=0;t<4;t++){
            const int fi = (wv*4 + t)*8 + k8;
            const bf16x8 bh = *(const bf16x8*)(whi + (size_t)fi*512 + lane*8);
            const bf16x8 bl = *(const bf16x8*)(wlo + (size_t)fi*512 + lane*8);
            acc[t] = __builtin_amdgcn_mfma_f32_16x16x32_bf16(ah, bh, acc[t], 0, 0, 0);
            acc[t] = __builtin_amdgcn_mfma_f32_16x16x32_bf16(ah, bl, acc[t], 0, 0, 0);
            acc[t] = __builtin_amdgcn_mfma_f32_16x16x32_bf16(al, bh, acc[t], 0, 0, 0);
        }
    }

    #pragma unroll
    for (int i=0;i<4;i++){
        const int node = n0 + quad*4 + i;
        if (node < N_NODES){
            #pragma unroll
            for (int t=0;t<4;t++){
                const int n = (wv*4 + t)*16 + fcol;
                xout[(size_t)node*C + n] = softplusf(acc[t][i] + b[n]);
            }
        }
    }
}

// ---------------------------------------------------------------- mean pool, run-merged (batch is sorted)
__global__ __launch_bounds__(256) void pool_kernel(
    const float* __restrict__ x, const int* __restrict__ batch,
    float* __restrict__ sums, float* __restrict__ cnts)
{
    constexpr int NPB = 32;
    const int n0 = blockIdx.x * NPB;
    const int c  = threadIdx.x;
    int gprev = batch[n0];
    float run = 0.0f, crun = 0.0f;
    for (int i=0;i<NPB;i++){
        const int n = n0 + i;
        if (n >= N_NODES) break;
        const int g = batch[n];
        if (g != gprev){
            atomicAdd(&sums[(size_t)gprev*HID + c], run);
            if (c == 0) atomicAdd(&cnts[gprev], crun);
            run = 0.0f; crun = 0.0f; gprev = g;
        }
        run  += x[(size_t)n*HID + c];
        crun += 1.0f;
    }
    atomicAdd(&sums[(size_t)gprev*HID + c], run);
    if (c == 0) atomicAdd(&cnts[gprev], crun);
}

// ---------------------------------------------------------------- readout MLP (one block per graph)
__global__ __launch_bounds__(256) void readout_kernel(
    const float* __restrict__ sums, const float* __restrict__ cnts,
    const float* __restrict__ rw1, const float* __restrict__ rb1,
    const float* __restrict__ rw2, const float* __restrict__ rb2,
    const float* __restrict__ rw3, const float* __restrict__ rb3,
    float* __restrict__ out)
{
    __shared__ float g[HID];
    __shared__ float h[HID];
    __shared__ float h2[HID/2];
    __shared__ float red[256];
    const int gi = blockIdx.x;
    const int t  = threadIdx.x;
    const float cnt = fmaxf(cnts[gi], 1.0f);
    g[t] = sums[(size_t)gi*HID + t] / cnt;
    __syncthreads();
    float acc = rb1[t];
    for (int k=0;k<HID;k++) acc = fmaf(g[k], rw1[(size_t)k*HID + t], acc);
    h[t] = softplusf(acc);
    __syncthreads();
    if (t < HID/2){
        float a2 = rb2[t];
        for (int k=0;k<HID;k++) a2 = fmaf(h[k], rw2[(size_t)k*(HID/2) + t], a2);
        h2[t] = softplusf(a2);
    }
    __syncthreads();
    red[t] = (t < HID/2) ? h2[t]*rw3[t] : 0.0f;
    __syncthreads();
    for (int s2=128; s2>0; s2>>=1){
        if (t < s2) red[t] += red[t+s2];
        __syncthreads();
    }
    if (t == 0) out[gi] = red[0] + rb3[0];
}

// ---------------------------------------------------------------- launcher
extern "C" void kernel_launch(void* const* d_in, const int* in_sizes, int n_in,
                              void* d_out, int out_size, void* d_ws, size_t ws_size,
                              hipStream_t stream)
{
    const int*   x_atoms = (const int*)d_in[0];
    const int*   eidx    = (const int*)d_in[1];
    const int*   src     = eidx;               // edge_index[0]
    const int*   dst     = eidx + N_EDGES;     // edge_index[1]
    const float* ea      = (const float*)d_in[2];
    const int*   batch   = (const int*)d_in[3];
    const float* emb     = (const float*)d_in[4];
    const float* ew1_0   = (const float*)d_in[5];
    const float* eb1_0   = (const float*)d_in[6];
    const float* ew2_0   = (const float*)d_in[7];
    const float* eb2_0   = (const float*)d_in[8];
    const float* nw_0    = (const float*)d_in[9];
    const float* nb_0    = (const float*)d_in[10];
    const float* ew1     = (const float*)d_in[11];
    const float* eb1     = (const float*)d_in[12];
    const float* ew2     = (const float*)d_in[13];
    const float* eb2     = (const float*)d_in[14];
    const float* nw      = (const float*)d_in[15];
    const float* nb      = (const float*)d_in[16];
    const float* rw1     = (const float*)d_in[17];
    const float* rb1     = (const float*)d_in[18];
    const float* rw2     = (const float*)d_in[19];
    const float* rb2     = (const float*)d_in[20];
    const float* rw3     = (const float*)d_in[21];
    const float* rb3     = (const float*)d_in[22];
    float* out = (float*)d_out;

    float* x    = (float*)d_ws;
    float* agg  = x   + (size_t)N_NODES*HID;
    float* sums = agg + (size_t)N_NODES*HID;
    float* cnts = sums + (size_t)N_GRAPHS*HID;
    unsigned short* whi  = (unsigned short*)(cnts + N_GRAPHS);
    unsigned short* wlo  = whi  + (size_t)3*128*512;
    unsigned short* nwhi = wlo  + (size_t)3*128*512;
    unsigned short* nwlo = nwhi + (size_t)3*128*512;
    unsigned short* w92hi  = nwlo  + (size_t)3*128*512;   // 18 frags
    unsigned short* w92lo  = w92hi + (size_t)18*512;
    unsigned short* nw92hi = w92lo + (size_t)18*512;      // 48 frags
    unsigned short* nw92lo = nw92hi + (size_t)48*512;
    int* hist   = (int*)(nw92lo + (size_t)48*512);
    int* cursor = hist   + N_NODES;
    int* perm_s = cursor + N_NODES;
    int* src_s  = perm_s + N_EDGES;
    int* dst_s  = src_s  + N_EDGES;

    // ---- counting sort of edges by dst (once per launch) ----
    hipMemsetAsync(hist, 0, N_NODES*sizeof(int), stream);
    hipLaunchKernelGGL(hist_kernel, dim3((N_EDGES+255)/256), dim3(256), 0, stream, dst, hist);
    hipLaunchKernelGGL(scan_kernel, dim3(1), dim3(1024), 0, stream, hist, cursor);
    hipLaunchKernelGGL(scatter_kernel, dim3((N_EDGES+255)/256), dim3(256), 0, stream,
                       src, dst, cursor, perm_s, src_s, dst_s);

    // ---- pack weights for MFMA ----
    hipLaunchKernelGGL(pack_w_kernel, dim3(384), dim3(256), 0, stream, ew2, whi, wlo);
    hipLaunchKernelGGL(pack_w_kernel, dim3(384), dim3(256), 0, stream, nw, nwhi, nwlo);
    hipLaunchKernelGGL(pack_w_pad_kernel, dim3(18), dim3(256), 0, stream, ew2_0, EMB_DIM, EMB_DIM, EMB_DIM, w92hi, w92lo);
    hipLaunchKernelGGL(pack_w_pad_kernel, dim3(48), dim3(256), 0, stream, nw_0, EMB_DIM, HID, HID, nw92hi, nw92lo);

    // ---- layer 0 (C = 92), MFMA ----
    hipLaunchKernelGGL(gather_emb_kernel, dim3(N_NODES), dim3(128), 0, stream, x_atoms, emb, x);
    hipMemsetAsync(agg, 0, (size_t)N_NODES*EMB_DIM*sizeof(float), stream);
    hipLaunchKernelGGL(edge_conv92_mfma_kernel, dim3(((N_EDGES/32)+7)/8*8), dim3(256), 0, stream,
                       perm_s, src_s, dst_s, ea, ew1_0, eb1_0, w92hi, w92lo, eb2_0, x, agg);
    hipLaunchKernelGGL(node_update92_mfma_kernel, dim3((N_NODES+15)/16), dim3(256), 0, stream,
                       agg, nw92hi, nw92lo, nb_0, x);

    // ---- layers 1..3 (C = 256), MFMA, EPB=64 ----
    const int NWIN64 = (N_EDGES + 63) / 64;           // 4688 (divisible by 8)
    for (int i=0;i<3;i++){
        hipMemsetAsync(agg, 0, (size_t)N_NODES*HID*sizeof(float), stream);
        hipLaunchKernelGGL(edge_conv256_mfma_kernel, dim3((NWIN64+7)/8*8), dim3(256), 0, stream,
                           perm_s, src_s, dst_s, ea,
                           ew1 + (size_t)i*4*HID, eb1 + (size_t)i*HID,
                           whi + (size_t)i*128*512, wlo + (size_t)i*128*512,
                           eb2 + (size_t)i*HID,
                           x, agg);
        hipLaunchKernelGGL(node_update_mfma_kernel, dim3((N_NODES+15)/16), dim3(256), 0, stream,
                           agg, nwhi + (size_t)i*128*512, nwlo + (size_t)i*128*512,
                           nb + (size_t)i*HID, x);
    }

    // ---- pool + readout ----
    hipMemsetAsync(sums, 0, ((size_t)N_GRAPHS*HID + N_GRAPHS)*sizeof(float), stream);
    hipLaunchKernelGGL(pool_kernel, dim3((N_NODES+31)/32), dim3(256), 0, stream, x, batch, sums, cnts);
    hipLaunchKernelGGL(readout_kernel, dim3(N_GRAPHS), dim3(256), 0, stream,
                       sums, cnts, rw1, rb1, rw2, rb2, rw3, rb3, out);
}

// Round 11
// 752.950 us; speedup vs baseline: 1.6769x; 1.0504x over previous
//
#include <hip/hip_runtime.h>
#include <math.h>

#define N_NODES  25000
#define N_EDGES  300000
#define N_GRAPHS 256
#define EMB_DIM  92
#define HID      256

typedef short bf16x8 __attribute__((ext_vector_type(8)));
typedef float f32x4  __attribute__((ext_vector_type(4)));

// fast softplus == jax.nn.softplus to ~1e-6 abs
__device__ __forceinline__ float softplusf(float x){
    return fmaxf(x, 0.0f) + __logf(1.0f + __expf(-fabsf(x)));
}
__device__ __forceinline__ unsigned short f2bf(float f){     // RNE (packers only)
    unsigned int u = __float_as_uint(f);
    unsigned int r = (u + 0x7FFFu + ((u >> 16) & 1u)) >> 16;
    return (unsigned short)r;
}
__device__ __forceinline__ unsigned short f2bf_trunc(float f){   // 1-op truncation
    return (unsigned short)(__float_as_uint(f) >> 16);
}
__device__ __forceinline__ float bf2f(unsigned short b){
    return __uint_as_float(((unsigned int)b) << 16);
}
// truncation hi/lo split (A operand of node updates; 3-MFMA scheme)
__device__ __forceinline__ void split_bf(float h, unsigned short& hi, unsigned short& lo){
    const unsigned int u = __float_as_uint(h);
    hi = (unsigned short)(u >> 16);
    const float r = h - __uint_as_float(u & 0xFFFF0000u);
    lo = (unsigned short)(__float_as_uint(r) >> 16);
}
// XCD-contiguity swizzle (perf heuristic only)
__device__ __forceinline__ int xcd_window(int nwin){
    const int per = (nwin + 7) >> 3;
    const int win = (blockIdx.x & 7) * per + (blockIdx.x >> 3);
    return (win < nwin) ? win : -1;
}

// ---------------------------------------------------------------- embedding gather
__global__ void gather_emb_kernel(const int* __restrict__ atoms,
                                  const float* __restrict__ emb,
                                  float* __restrict__ x)
{
    const int n = blockIdx.x;
    const int c = threadIdx.x;
    if (c < EMB_DIM){
        const int a = atoms[n];
        x[(size_t)n*EMB_DIM + c] = emb[(size_t)a*EMB_DIM + c];
    }
}

// ---------------------------------------------------------------- counting sort by dst
__global__ __launch_bounds__(256) void hist_kernel(const int* __restrict__ dst, int* __restrict__ hist){
    const int e = blockIdx.x*256 + threadIdx.x;
    if (e < N_EDGES) atomicAdd(&hist[dst[e]], 1);
}

__global__ __launch_bounds__(1024) void scan_kernel(const int* __restrict__ hist, int* __restrict__ cursor){
    __shared__ int chunk[1024];
    const int t = threadIdx.x;
    const int base = t*25;                     // 1024*25 = 25600 >= 25000
    int local[25];
    int s = 0;
    #pragma unroll
    for (int i=0;i<25;i++){
        const int idx = base+i;
        const int v = (idx < N_NODES) ? hist[idx] : 0;
        local[i] = s; s += v;
    }
    chunk[t] = s;
    __syncthreads();
    for (int off=1; off<1024; off<<=1){
        int v = (t >= off) ? chunk[t-off] : 0;
        __syncthreads();
        chunk[t] += v;
        __syncthreads();
    }
    const int pre = (t > 0) ? chunk[t-1] : 0;
    #pragma unroll
    for (int i=0;i<25;i++){
        const int idx = base+i;
        if (idx < N_NODES) cursor[idx] = pre + local[i];
    }
}

// scatter + ea pre-gather: edge-conv staging becomes fully coalesced
__global__ __launch_bounds__(256) void scatter_kernel(const int* __restrict__ src, const int* __restrict__ dst,
                                                      const float* __restrict__ ea,
                                                      int* __restrict__ cursor,
                                                      int* __restrict__ src_s, int* __restrict__ dst_s,
                                                      float* __restrict__ ea_s){
    const int e = blockIdx.x*256 + threadIdx.x;
    if (e < N_EDGES){
        const int d = dst[e];
        const int pos = atomicAdd(&cursor[d], 1);
        src_s[pos] = src[e];
        dst_s[pos] = d;
        const float4 a = *(const float4*)(ea + (size_t)e*4);
        *(float4*)(ea_s + (size_t)pos*4) = a;
    }
}

// ---------------------------------------------------------------- pack [3][256][256] weights into MFMA B-frag hi/lo bf16 (K=256, 8 k-tiles)
__global__ __launch_bounds__(256) void pack_w_kernel(const float* __restrict__ w,
                                                     unsigned short* __restrict__ whi,
                                                     unsigned short* __restrict__ wlo)
{
    const int f     = blockIdx.x;          // 0..383
    const int layer = f >> 7;
    const int rem   = f & 127;
    const int ntile = rem >> 3;
    const int k8    = rem & 7;
    for (int i = threadIdx.x; i < 512; i += 256){
        const int lane = i >> 3, j = i & 7;
        const int k = k8*32 + (lane >> 4)*8 + j;
        const int n = ntile*16 + (lane & 15);
        const float v = w[(size_t)layer*HID*HID + (size_t)k*HID + n];
        const unsigned short hb = f2bf(v);
        whi[(size_t)f*512 + i] = hb;
        wlo[(size_t)f*512 + i] = f2bf(v - bf2f(hb));
    }
}

// ---------------------------------------------------------------- generic padded packer: [Kin x Nin] -> frags (3 k-tiles of 32, zero-pad)
__global__ __launch_bounds__(256) void pack_w_pad_kernel(const float* __restrict__ w,
                                                         int Kin, int Nin, int ldn,
                                                         unsigned short* __restrict__ whi,
                                                         unsigned short* __restrict__ wlo)
{
    const int f  = blockIdx.x;
    const int k8 = f % 3;
    const int ntile = f / 3;
    for (int i = threadIdx.x; i < 512; i += 256){
        const int lane = i >> 3, j = i & 7;
        const int k = k8*32 + (lane >> 4)*8 + j;
        const int n = ntile*16 + (lane & 15);
        float v = 0.0f;
        if (k < Kin && n < Nin) v = w[(size_t)k*ldn + n];
        const unsigned short hb = f2bf(v);
        whi[(size_t)f*512 + i] = hb;
        wlo[(size_t)f*512 + i] = f2bf(v - bf2f(hb));
    }
}

// ---------------------------------------------------------------- layer-0 edge conv MFMA (C=92, pad 96), 64 edges/block
// Wave wv = (mpair, ngrp): mpair = wv>>1 covers edges mpair*32..+31 (m-tiles 2*mpair,2*mpair+1),
// ngrp = wv&1 covers n-tiles ngrp*3..+2. (mpair,quad) owns a contiguous 8-edge dst-sorted chain.
// Edge e -> LDS row (e>>5)*32 + ((e>>2)&1)*16 + ((e>>3)&3)*4 + (e&3).
__global__ __launch_bounds__(256, 4) void edge_conv92_mfma_kernel(
    const int* __restrict__ src_s, const int* __restrict__ dst_s,
    const float* __restrict__ ea_s,
    const float* __restrict__ w1, const float* __restrict__ b1,
    const unsigned short* __restrict__ whi, const unsigned short* __restrict__ wlo,  // 18 frags
    const float* __restrict__ b2,
    const float* __restrict__ x92, float* __restrict__ agg92)
{
    constexpr int C = EMB_DIM;     // 92
    constexpr int KP = 96;
    constexpr int LDA = 104;
    constexpr int EPB = 64;
    constexpr int NWIN = (N_EDGES + EPB - 1) / EPB;   // 4688
    __shared__ unsigned short aHi[EPB][LDA];   // 13.3 KB
    __shared__ float eaS[EPB][4];
    __shared__ int   srcS[EPB];
    __shared__ int   dstS[EPB];

    const int win = xcd_window(NWIN);
    if (win < 0) return;
    const int e0  = win * EPB;
    const int tid = threadIdx.x;

    {
        const int e = tid >> 2, comp = tid & 3;
        const int eid = min(e0 + e, N_EDGES-1);
        eaS[e][comp] = ea_s[(size_t)eid*4 + comp];
        if (tid < EPB){
            const int eid2 = min(e0 + tid, N_EDGES-1);
            srcS[tid] = src_s[eid2];
            dstS[tid] = dst_s[eid2];
        }
    }
    __syncthreads();

    // phase 1: h1 = softplus(ea@w1+b1), K zero-padded to 96; rows chain-permuted
    for (int idx = tid; idx < EPB*KP; idx += 256){
        const int e = idx / KP, k = idx - e*KP;
        float h = 0.0f;
        if (k < C){
            const float4 a = *(const float4*)&eaS[e][0];
            h = softplusf(fmaf(a.x, w1[k], fmaf(a.y, w1[C+k],
                          fmaf(a.z, w1[2*C+k], fmaf(a.w, w1[3*C+k], b1[k])))));
        }
        const int row = (e>>5)*32 + ((e>>2)&1)*16 + ((e>>3)&3)*4 + (e&3);
        aHi[row][k] = f2bf_trunc(h);
    }
    __syncthreads();

    const int lane = tid & 63, wv = tid >> 6;
    const int quad = lane >> 4, fcol = lane & 15;
    const int mpair = wv >> 1;
    const int ngrp  = wv & 1;

    f32x4 acc[2][3];
    #pragma unroll
    for (int m=0;m<2;m++)
        #pragma unroll
        for (int t=0;t<3;t++)
            #pragma unroll
            for (int j=0;j<4;j++) acc[m][t][j] = 0.0f;

    for (int k8=0;k8<3;k8++){
        bf16x8 ah[2];
        #pragma unroll
        for (int m=0;m<2;m++)
            ah[m] = *(const bf16x8*)(&aHi[mpair*32 + m*16 + fcol][0] + k8*32 + quad*8);
        #pragma unroll
        for (int t=0;t<3;t++){
            const int fi = (ngrp*3 + t)*3 + k8;
            const bf16x8 bh = *(const bf16x8*)(whi + (size_t)fi*512 + lane*8);
            const bf16x8 bl = *(const bf16x8*)(wlo + (size_t)fi*512 + lane*8);
            #pragma unroll
            for (int m=0;m<2;m++){
                acc[m][t] = __builtin_amdgcn_mfma_f32_16x16x32_bf16(ah[m], bh, acc[m][t], 0, 0, 0);
                acc[m][t] = __builtin_amdgcn_mfma_f32_16x16x32_bf16(ah[m], bl, acc[m][t], 0, 0, 0);
            }
        }
    }

    int   ncol[3]; float bb[3];
    #pragma unroll
    for (int t=0;t<3;t++){
        ncol[t] = (ngrp*3 + t)*16 + fcol;
        bb[t] = (ncol[t] < C) ? b2[ncol[t]] : 0.0f;
    }

    // epilogue: 8-edge chain at ebase; value of chain edge j: acc[j>>2][t][j&3]
    const int ebase = mpair*32 + quad*8;
    float xv[8][3];
    #pragma unroll
    for (int j=0;j<8;j++){
        const int s = srcS[ebase + j];
        const bool valid = (e0 + ebase + j) < N_EDGES;
        #pragma unroll
        for (int t=0;t<3;t++)
            xv[j][t] = (valid && ncol[t] < C) ? x92[(size_t)s*C + ncol[t]] : 0.0f;
    }

    int dprev = dstS[ebase];
    float run[3] = {0.f,0.f,0.f};
    #pragma unroll
    for (int j=0;j<8;j++){
        const int d = dstS[ebase + j];
        if (d != dprev){
            #pragma unroll
            for (int t=0;t<3;t++){
                if (ncol[t] < C) atomicAdd(&agg92[(size_t)dprev*C + ncol[t]], run[t]);
                run[t] = 0.0f;
            }
            dprev = d;
        }
        #pragma unroll
        for (int t=0;t<3;t++)
            run[t] += (acc[j>>2][t][j&3] + bb[t]) * xv[j][t];
    }
    #pragma unroll
    for (int t=0;t<3;t++)
        if (ncol[t] < C) atomicAdd(&agg92[(size_t)dprev*C + ncol[t]], run[t]);
}

// ---------------------------------------------------------------- node update 92->256 MFMA
__global__ __launch_bounds__(256) void node_update92_mfma_kernel(
    const float* __restrict__ agg92,
    const unsigned short* __restrict__ whi, const unsigned short* __restrict__ wlo,  // 48 frags
    const float* __restrict__ b, float* __restrict__ xout)
{
    constexpr int C = EMB_DIM;
    constexpr int KP = 96;
    constexpr int LDA = 104;
    __shared__ unsigned short aHi[16][LDA];
    __shared__ unsigned short aLo[16][LDA];

    const int n0  = blockIdx.x * 16;
    const int tid = threadIdx.x;

    for (int idx = tid; idx < 16*KP; idx += 256){
        const int i = idx / KP, k = idx - i*KP;
        const int node = n0 + i;
        float v = 0.0f;
        if (k < C && node < N_NODES) v = agg92[(size_t)node*C + k];
        unsigned short hb, lb;
        split_bf(v, hb, lb);
        aHi[i][k] = hb;
        aLo[i][k] = lb;
    }
    __syncthreads();

    const int lane = tid & 63, wv = tid >> 6;
    const int quad = lane >> 4, fcol = lane & 15;

    f32x4 acc[4];
    #pragma unroll
    for (int t=0;t<4;t++)
        #pragma unroll
        for (int j=0;j<4;j++) acc[t][j] = 0.0f;

    const unsigned short* aHrow = &aHi[fcol][0];
    const unsigned short* aLrow = &aLo[fcol][0];

    for (int k8=0;k8<3;k8++){
        const bf16x8 ah = *(const bf16x8*)(aHrow + k8*32 + quad*8);
        const bf16x8 al = *(const bf16x8*)(aLrow + k8*32 + quad*8);
        #pragma unroll
        for (int t=0;t<4;t++){
            const int fi = (wv*4 + t)*3 + k8;
            const bf16x8 bh = *(const bf16x8*)(whi + (size_t)fi*512 + lane*8);
            const bf16x8 bl = *(const bf16x8*)(wlo + (size_t)fi*512 + lane*8);
            acc[t] = __builtin_amdgcn_mfma_f32_16x16x32_bf16(ah, bh, acc[t], 0, 0, 0);
            acc[t] = __builtin_amdgcn_mfma_f32_16x16x32_bf16(ah, bl, acc[t], 0, 0, 0);
            acc[t] = __builtin_amdgcn_mfma_f32_16x16x32_bf16(al, bh, acc[t], 0, 0, 0);
        }
    }

    #pragma unroll
    for (int i=0;i<4;i++){
        const int node = n0 + quad*4 + i;
        if (node < N_NODES){
            #pragma unroll
            for (int t=0;t<4;t++){
                const int n = (wv*4 + t)*16 + fcol;
                xout[(size_t)node*HID + n] = softplusf(acc[t][i] + b[n]);
            }
        }
    }
}

// ---------------------------------------------------------------- layers 1-3 edge conv, MFMA, 64 edges/block
// Quad q owns a CONTIGUOUS 16-edge dst-sorted chain. Edge e (q=e>>4, j=e&15)
// lives in MFMA m-tile j>>2, row q*4+(j&3).
__global__ __launch_bounds__(256, 4) void edge_conv256_mfma_kernel(
    const int* __restrict__ src_s, const int* __restrict__ dst_s,
    const float* __restrict__ ea_s,
    const float* __restrict__ w1, const float* __restrict__ b1,
    const unsigned short* __restrict__ whi, const unsigned short* __restrict__ wlo,
    const float* __restrict__ b2,
    const float* __restrict__ x, float* __restrict__ agg)
{
    constexpr int C = HID;
    constexpr int LDA = C + 8;                 // 528 B row stride
    constexpr int EPB = 64;
    constexpr int NWIN = (N_EDGES + EPB - 1) / EPB;   // 4688
    __shared__ unsigned short aHi[EPB][LDA];   // 33.8 KB
    __shared__ float eaS[EPB][4];
    __shared__ int   srcS[EPB];
    __shared__ int   dstS[EPB];

    const int win = xcd_window(NWIN);
    if (win < 0) return;
    const int e0  = win * EPB;
    const int tid = threadIdx.x;

    // stage ea_s (coalesced), src, dst
    {
        const int e = tid >> 2, comp = tid & 3;
        const int eid = min(e0 + e, N_EDGES-1);
        eaS[e][comp] = ea_s[(size_t)eid*4 + comp];
        if (tid < EPB){
            const int eid2 = min(e0 + tid, N_EDGES-1);
            srcS[tid] = src_s[eid2];
            dstS[tid] = dst_s[eid2];
        }
    }
    __syncthreads();

    // phase 1: h1 = softplus(ea@w1+b1) -> bf16 LDS rows permuted per chain map
    {
        const int k = tid;
        const float w10 = w1[k], w11 = w1[C+k], w12 = w1[2*C+k], w13 = w1[3*C+k];
        const float bk  = b1[k];
        #pragma unroll
        for (int e=0;e<EPB;e++){
            const float4 a = *(const float4*)&eaS[e][0];
            const float v = fmaf(a.x,w10,fmaf(a.y,w11,fmaf(a.z,w12,fmaf(a.w,w13,bk))));
            const int q = e >> 4, j = e & 15;
            aHi[(j>>2)*16 + q*4 + (j&3)][k] = f2bf_trunc(softplusf(v));
        }
    }
    __syncthreads();

    const int lane = tid & 63, wv = tid >> 6;
    const int quad = lane >> 4, fcol = lane & 15;

    f32x4 acc[4][4];     // [m-tile][n-tile]
    #pragma unroll
    for (int m=0;m<4;m++)
        #pragma unroll
        for (int t=0;t<4;t++)
            #pragma unroll
            for (int j=0;j<4;j++) acc[m][t][j] = 0.0f;

    for (int k8=0;k8<8;k8++){
        bf16x8 ah[4];
        #pragma unroll
        for (int m=0;m<4;m++)
            ah[m] = *(const bf16x8*)(&aHi[m*16 + fcol][0] + k8*32 + quad*8);
        #pragma unroll
        for (int t=0;t<4;t++){
            const int fi = (wv*4 + t)*8 + k8;
            const bf16x8 bh = *(const bf16x8*)(whi + (size_t)fi*512 + lane*8);
            const bf16x8 bl = *(const bf16x8*)(wlo + (size_t)fi*512 + lane*8);
            #pragma unroll
            for (int m=0;m<4;m++){
                acc[m][t] = __builtin_amdgcn_mfma_f32_16x16x32_bf16(ah[m], bh, acc[m][t], 0, 0, 0);
                acc[m][t] = __builtin_amdgcn_mfma_f32_16x16x32_bf16(ah[m], bl, acc[m][t], 0, 0, 0);
            }
        }
    }

    // epilogue: quad owns window edges quad*16..+15; value of edge j: acc[j>>2][t][j&3]
    float bb[4];
    #pragma unroll
    for (int t=0;t<4;t++) bb[t] = b2[(wv*4 + t)*16 + fcol];

    const int ebase = quad*16;
    int dprev = dstS[ebase];
    float run[4] = {0.f,0.f,0.f,0.f};
    #pragma unroll
    for (int jj=0; jj<16; jj+=4){
        float xv[4][4];
        #pragma unroll
        for (int j2=0;j2<4;j2++){
            const int j = jj + j2;
            const int s = srcS[ebase + j];
            const bool valid = (e0 + ebase + j) < N_EDGES;
            #pragma unroll
            for (int t=0;t<4;t++)
                xv[j2][t] = valid ? x[(size_t)s*C + (wv*4 + t)*16 + fcol] : 0.0f;
        }
        #pragma unroll
        for (int j2=0;j2<4;j2++){
            const int j = jj + j2;
            const int d = dstS[ebase + j];
            if (d != dprev){
                #pragma unroll
                for (int t=0;t<4;t++){
                    atomicAdd(&agg[(size_t)dprev*C + (wv*4 + t)*16 + fcol], run[t]);
                    run[t] = 0.0f;
                }
                dprev = d;
            }
            const int m = j >> 2, i = j & 3;
            #pragma unroll
            for (int t=0;t<4;t++)
                run[t] += (acc[m][t][i] + bb[t]) * xv[j2][t];
        }
    }
    #pragma unroll
    for (int t=0;t<4;t++)
        atomicAdd(&agg[(size_t)dprev*C + (wv*4 + t)*16 + fcol], run[t]);
}

// ---------------------------------------------------------------- node update MFMA (CIN=256)
__global__ __launch_bounds__(256) void node_update_mfma_kernel(
    const float* __restrict__ agg,
    const unsigned short* __restrict__ whi, const unsigned short* __restrict__ wlo,
    const float* __restrict__ b, float* __restrict__ xout)
{
    constexpr int C = HID;
    constexpr int LDA = C + 8;
    __shared__ unsigned short aHi[16][LDA];
    __shared__ unsigned short aLo[16][LDA];

    const int n0  = blockIdx.x * 16;
    const int tid = threadIdx.x;

    #pragma unroll
    for (int it=0; it<16; it++){
        const int node = n0 + it;
        const float v = (node < N_NODES) ? agg[(size_t)node*C + tid] : 0.0f;
        unsigned short hb, lb;
        split_bf(v, hb, lb);
        aHi[it][tid] = hb;
        aLo[it][tid] = lb;
    }
    __syncthreads();

    const int lane = tid & 63, wv = tid >> 6;
    const int quad = lane >> 4, fcol = lane & 15;

    f32x4 acc[4];
    #pragma unroll
    for (int t=0;t<4;t++)
        #pragma unroll
        for (int j=0;j<4;j++) acc[t][j] = 0.0f;

    const unsigned short* aHrow = &aHi[fcol][0];
    const unsigned short* aLrow = &aLo[fcol][0];

    for (int k8=0;k8<8;k8++){
        const bf16x8 ah = *(const bf16x8*)(aHrow + k8*32 + quad*8);
        const bf16x8 al = *(const bf16x8*)(aLrow + k8*32 + quad*8);
        #pragma unroll
        for (int t=0;t<4;t++){
            const int fi = (wv*4 + t)*8 + k8;
            const bf16x8 bh = *(const bf16x8*)(whi + (size_t)fi*512 + lane*8);
            const bf16x8 bl = *(const bf16x8*)(wlo + (size_t)fi*512 + lane*8);
            acc[t] = __builtin_amdgcn_mfma_f32_16x16x32_bf16(ah, bh, acc[t], 0, 0, 0);
            acc[t] = __builtin_amdgcn_mfma_f32_16x16x32_bf16(ah, bl, acc[t], 0, 0, 0);
            acc[t] = __builtin_amdgcn_mfma_f32_16x16x32_bf16(al, bh, acc[t], 0, 0, 0);
        }
    }

    #pragma unroll
    for (int i=0;i<4;i++){
        const int node = n0 + quad*4 + i;
        if (node < N_NODES){
            #pragma unroll
            for (int t=0;t<4;t++){
                const int n = (wv*4 + t)*16 + fcol;
                xout[(size_t)node*C + n] = softplusf(acc[t][i] + b[n]);
            }
        }
    }
}

// ---------------------------------------------------------------- mean pool, run-merged (batch is sorted)
__global__ __launch_bounds__(256) void pool_kernel(
    const float* __restrict__ x, const int* __restrict__ batch,
    float* __restrict__ sums, float* __restrict__ cnts)
{
    constexpr int NPB = 32;
    const int n0 = blockIdx.x * NPB;
    const int c  = threadIdx.x;
    int gprev = batch[n0];
    float run = 0.0f, crun = 0.0f;
    for (int i=0;i<NPB;i++){
        const int n = n0 + i;
        if (n >= N_NODES) break;
        const int g = batch[n];
        if (g != gprev){
            atomicAdd(&sums[(size_t)gprev*HID + c], run);
            if (c == 0) atomicAdd(&cnts[gprev], crun);
            run = 0.0f; crun = 0.0f; gprev = g;
        }
        run  += x[(size_t)n*HID + c];
        crun += 1.0f;
    }
    atomicAdd(&sums[(size_t)gprev*HID + c], run);
    if (c == 0) atomicAdd(&cnts[gprev], crun);
}

// ---------------------------------------------------------------- readout MLP (one block per graph)
__global__ __launch_bounds__(256) void readout_kernel(
    const float* __restrict__ sums, const float* __restrict__ cnts,
    const float* __restrict__ rw1, const float* __restrict__ rb1,
    const float* __restrict__ rw2, const float* __restrict__ rb2,
    const float* __restrict__ rw3, const float* __restrict__ rb3,
    float* __restrict__ out)
{
    __shared__ float g[HID];
    __shared__ float h[HID];
    __shared__ float h2[HID/2];
    __shared__ float red[256];
    const int gi = blockIdx.x;
    const int t  = threadIdx.x;
    const float cnt = fmaxf(cnts[gi], 1.0f);
    g[t] = sums[(size_t)gi*HID + t] / cnt;
    __syncthreads();
    float acc = rb1[t];
    for (int k=0;k<HID;k++) acc = fmaf(g[k], rw1[(size_t)k*HID + t], acc);
    h[t] = softplusf(acc);
    __syncthreads();
    if (t < HID/2){
        float a2 = rb2[t];
        for (int k=0;k<HID;k++) a2 = fmaf(h[k], rw2[(size_t)k*(HID/2) + t], a2);
        h2[t] = softplusf(a2);
    }
    __syncthreads();
    red[t] = (t < HID/2) ? h2[t]*rw3[t] : 0.0f;
    __syncthreads();
    for (int s2=128; s2>0; s2>>=1){
        if (t < s2) red[t] += red[t+s2];
        __syncthreads();
    }
    if (t == 0) out[gi] = red[0] + rb3[0];
}

// ---------------------------------------------------------------- launcher
extern "C" void kernel_launch(void* const* d_in, const int* in_sizes, int n_in,
                              void* d_out, int out_size, void* d_ws, size_t ws_size,
                              hipStream_t stream)
{
    const int*   x_atoms = (const int*)d_in[0];
    const int*   eidx    = (const int*)d_in[1];
    const int*   src     = eidx;               // edge_index[0]
    const int*   dst     = eidx + N_EDGES;     // edge_index[1]
    const float* ea      = (const float*)d_in[2];
    const int*   batch   = (const int*)d_in[3];
    const float* emb     = (const float*)d_in[4];
    const float* ew1_0   = (const float*)d_in[5];
    const float* eb1_0   = (const float*)d_in[6];
    const float* ew2_0   = (const float*)d_in[7];
    const float* eb2_0   = (const float*)d_in[8];
    const float* nw_0    = (const float*)d_in[9];
    const float* nb_0    = (const float*)d_in[10];
    const float* ew1     = (const float*)d_in[11];
    const float* eb1     = (const float*)d_in[12];
    const float* ew2     = (const float*)d_in[13];
    const float* eb2     = (const float*)d_in[14];
    const float* nw      = (const float*)d_in[15];
    const float* nb      = (const float*)d_in[16];
    const float* rw1     = (const float*)d_in[17];
    const float* rb1     = (const float*)d_in[18];
    const float* rw2     = (const float*)d_in[19];
    const float* rb2     = (const float*)d_in[20];
    const float* rw3     = (const float*)d_in[21];
    const float* rb3     = (const float*)d_in[22];
    float* out = (float*)d_out;

    float* x    = (float*)d_ws;
    float* agg  = x   + (size_t)N_NODES*HID;
    float* sums = agg + (size_t)N_NODES*HID;
    float* cnts = sums + (size_t)N_GRAPHS*HID;
    unsigned short* whi  = (unsigned short*)(cnts + N_GRAPHS);
    unsigned short* wlo  = whi  + (size_t)3*128*512;
    unsigned short* nwhi = wlo  + (size_t)3*128*512;
    unsigned short* nwlo = nwhi + (size_t)3*128*512;
    unsigned short* w92hi  = nwlo  + (size_t)3*128*512;   // 18 frags
    unsigned short* w92lo  = w92hi + (size_t)18*512;
    unsigned short* nw92hi = w92lo + (size_t)18*512;      // 48 frags
    unsigned short* nw92lo = nw92hi + (size_t)48*512;
    float* ea_s = (float*)(nw92lo + (size_t)48*512);      // [E,4] sorted edge attrs
    int* hist   = (int*)(ea_s + (size_t)N_EDGES*4);
    int* cursor = hist   + N_NODES;
    int* src_s  = cursor + N_NODES;
    int* dst_s  = src_s  + N_EDGES;

    // ---- counting sort of edges by dst (once per launch), with ea pre-gather ----
    hipMemsetAsync(hist, 0, N_NODES*sizeof(int), stream);
    hipLaunchKernelGGL(hist_kernel, dim3((N_EDGES+255)/256), dim3(256), 0, stream, dst, hist);
    hipLaunchKernelGGL(scan_kernel, dim3(1), dim3(1024), 0, stream, hist, cursor);
    hipLaunchKernelGGL(scatter_kernel, dim3((N_EDGES+255)/256), dim3(256), 0, stream,
                       src, dst, ea, cursor, src_s, dst_s, ea_s);

    // ---- pack weights for MFMA ----
    hipLaunchKernelGGL(pack_w_kernel, dim3(384), dim3(256), 0, stream, ew2, whi, wlo);
    hipLaunchKernelGGL(pack_w_kernel, dim3(384), dim3(256), 0, stream, nw, nwhi, nwlo);
    hipLaunchKernelGGL(pack_w_pad_kernel, dim3(18), dim3(256), 0, stream, ew2_0, EMB_DIM, EMB_DIM, EMB_DIM, w92hi, w92lo);
    hipLaunchKernelGGL(pack_w_pad_kernel, dim3(48), dim3(256), 0, stream, nw_0, EMB_DIM, HID, HID, nw92hi, nw92lo);

    const int NWIN64 = (N_EDGES + 63) / 64;           // 4688 (divisible by 8)

    // ---- layer 0 (C = 92), MFMA, EPB=64 ----
    hipLaunchKernelGGL(gather_emb_kernel, dim3(N_NODES), dim3(128), 0, stream, x_atoms, emb, x);
    hipMemsetAsync(agg, 0, (size_t)N_NODES*EMB_DIM*sizeof(float), stream);
    hipLaunchKernelGGL(edge_conv92_mfma_kernel, dim3((NWIN64+7)/8*8), dim3(256), 0, stream,
                       src_s, dst_s, ea_s, ew1_0, eb1_0, w92hi, w92lo, eb2_0, x, agg);
    hipLaunchKernelGGL(node_update92_mfma_kernel, dim3((N_NODES+15)/16), dim3(256), 0, stream,
                       agg, nw92hi, nw92lo, nb_0, x);

    // ---- layers 1..3 (C = 256), MFMA, EPB=64 ----
    for (int i=0;i<3;i++){
        hipMemsetAsync(agg, 0, (size_t)N_NODES*HID*sizeof(float), stream);
        hipLaunchKernelGGL(edge_conv256_mfma_kernel, dim3((NWIN64+7)/8*8), dim3(256), 0, stream,
                           src_s, dst_s, ea_s,
                           ew1 + (size_t)i*4*HID, eb1 + (size_t)i*HID,
                           whi + (size_t)i*128*512, wlo + (size_t)i*128*512,
                           eb2 + (size_t)i*HID,
                           x, agg);
        hipLaunchKernelGGL(node_update_mfma_kernel, dim3((N_NODES+15)/16), dim3(256), 0, stream,
                           agg, nwhi + (size_t)i*128*512, nwlo + (size_t)i*128*512,
                           nb + (size_t)i*HID, x);
    }

    // ---- pool + readout ----
    hipMemsetAsync(sums, 0, ((size_t)N_GRAPHS*HID + N_GRAPHS)*sizeof(float), stream);
    hipLaunchKernelGGL(pool_kernel, dim3((N_NODES+31)/32), dim3(256), 0, stream, x, batch, sums, cnts);
    hipLaunchKernelGGL(readout_kernel, dim3(N_GRAPHS), dim3(256), 0, stream,
                       sums, cnts, rw1, rb1, rw2, rb2, rw3, rb3, out);
}